// Round 11
// baseline (147.933 us; speedup 1.0000x reference)
//
#include <hip/hip_runtime.h>
#include <hip/hip_fp16.h>

// GCNRegressor: x[n,128] --GCNConv(W1)--> relu --GCNConv(W2)--> relu --@Wl+bl--> out[n]
// n=100000, E=1600000, IN=128, HID=64.
// R1-R10: CSR+gather, counting sort, fp16 features, MFMA GEMMs: 2913 -> 171 us.
// R11: 8-rows-per-VMEM gather (wave = 8 groups x 8 lanes, uint4/lane): 41.8us agg.
// R12/R13: dot2 + fewer slots: VALU -25% but dur +3..15%. LESSON: agg is
//      LATENCY-bound; issue all loads back-to-back, no branches in between.
// R14: 2 nodes per wave, software-pipelined (16 VMEM in flight): 162 -> 148.7.
// R15/R16/R17: CSR-build experiments. RULE: every 64B line of a store stream
//      must be filled by ONE block (write amp kills otherwise).
// R18/R19: block-major binned + values-to-LDS + transposed gbase.
// R20: scan-not-atomics + 1024-thr k_bfill: 133.2. BEST.
// R21: 4 nodes/wave (32 VMEM in flight): NEUTRAL (134.3) -- depth lever
//      saturated at 16 in flight; VGPR cost cancels extra MLP.
// R22: degree-class node lists (built in k_bfill). class0 (deg<=16, ~55%):
//      4 nodes x 2 slots per wave -- same 16-VMEM straight-line schedule,
//      half the per-node work, zero masking waste. class1 (deg>16): R20's
//      2-node x 4-slot kernel via list indirection. Slot work -45%, wave
//      count 50K -> 36K per agg. R13's lesson respected: degree uniformity
//      comes from partitioning, not in-wave branches.

#define SHIFT 9
#define BSZ   (1 << SHIFT)     // 512 nodes per bucket
#define NBMAX 256              // >= nb = 196
#define BIN_CH 1024            // edges per k_bin block (private region)
#define PMAX  11776            // bucket edge capacity (mean 8163, +40 sigma)

using f16x8 = __attribute__((ext_vector_type(8))) _Float16;
using f16x2 = __attribute__((ext_vector_type(2))) _Float16;
using f32x4 = __attribute__((ext_vector_type(4))) float;

// ---- Phase 1: per-block counting sort into private binned region ----
// binned[blk*BIN_CH + ex[bucket] ...] sorted by bucket; gbase[blk*(nb+1)+i] =
// exclusive prefix of this block's bucket counts (row i=nb = chunk total).
// pack: src(17b) | local_node(9b)<<17. Block 0 also zeroes the dummy hs row
// and the class counters.
__global__ __launch_bounds__(256) void k_bin(const int* __restrict__ src,
                                             const int* __restrict__ dst,
                                             unsigned* __restrict__ binned,
                                             int* __restrict__ gbase,
                                             __half* __restrict__ hs,
                                             int* __restrict__ clscnt,
                                             int n, int nb, int E) {
    if (blockIdx.x == 0 && threadIdx.x < 8) {
        uint4 z = {0u, 0u, 0u, 0u};
        reinterpret_cast<uint4*>(hs + ((size_t)n << 6))[threadIdx.x] = z;
        if (threadIdx.x < 2) clscnt[threadIdx.x] = 0;
    }
    __shared__ int h[NBMAX];
    __shared__ int ex[NBMAX + 1];
    __shared__ int cur[NBMAX];
    __shared__ int stmp[256];
    const int t = threadIdx.x;
    const int blk = blockIdx.x;
    const int beg = blk * BIN_CH;
    for (int i = t; i < NBMAX; i += 256) h[i] = 0;
    __syncthreads();
    const int e4 = beg + t * 4;
    const bool act = e4 < E;               // E % 4 == 0: all-or-nothing per thread
    int4 d4 = {0, 0, 0, 0};
    if (act) {
        d4 = *reinterpret_cast<const int4*>(dst + e4);
        atomicAdd(&h[d4.x >> SHIFT], 1);
        atomicAdd(&h[d4.y >> SHIFT], 1);
        atomicAdd(&h[d4.z >> SHIFT], 1);
        atomicAdd(&h[d4.w >> SHIFT], 1);
    }
    __syncthreads();
    const int hv = (t < nb) ? h[t] : 0;
    stmp[t] = hv;
    __syncthreads();
    for (int off = 1; off < 256; off <<= 1) {
        int u = (t >= off) ? stmp[t - off] : 0;
        __syncthreads();
        stmp[t] += u;
        __syncthreads();
    }
    if (t <= nb) ex[t] = stmp[t] - ((t < nb) ? h[t] : 0);  // t==nb -> chunk total
    __syncthreads();
    if (t < nb) cur[t] = ex[t];
    if (t <= nb) gbase[(size_t)blk * (nb + 1) + t] = ex[t];  // coalesced, private
    __syncthreads();
    if (act) {
        const int4 s4 = *reinterpret_cast<const int4*>(src + e4);
        int b0 = d4.x >> SHIFT, b1 = d4.y >> SHIFT;
        int b2 = d4.z >> SHIFT, b3 = d4.w >> SHIFT;
        int p0 = atomicAdd(&cur[b0], 1);
        int p1 = atomicAdd(&cur[b1], 1);
        int p2 = atomicAdd(&cur[b2], 1);
        int p3 = atomicAdd(&cur[b3], 1);
        binned[beg + p0] = (unsigned)s4.x | ((unsigned)(d4.x & (BSZ - 1)) << 17);
        binned[beg + p1] = (unsigned)s4.y | ((unsigned)(d4.y & (BSZ - 1)) << 17);
        binned[beg + p2] = (unsigned)s4.z | ((unsigned)(d4.z & (BSZ - 1)) << 17);
        binned[beg + p3] = (unsigned)s4.w | ((unsigned)(d4.w & (BSZ - 1)) << 17);
    }
}

// ---- Phase 1.5: transpose gbase[nblk][nb+1] -> gbaseT[nb+1][nblk] so k_bfill
// reads contiguous coalesced rows instead of stride-788B columns. ----
#define TD 32
__global__ __launch_bounds__(256) void k_xpose(const int* __restrict__ gbase,
                                               int* __restrict__ gbaseT,
                                               int nblk, int nbp1) {
    __shared__ int tile[TD][TD + 1];
    const int ctiles = (nbp1 + TD - 1) / TD;
    const int bx = blockIdx.x % ctiles;     // bucket-dim tile
    const int by = blockIdx.x / ctiles;     // blk-dim tile
    const int c0 = bx * TD, r0 = by * TD;
    const int tx = threadIdx.x & 31, ty = threadIdx.x >> 5;
    for (int dy = ty; dy < TD; dy += 8) {
        int r = r0 + dy, c = c0 + tx;
        tile[dy][tx] = (r < nblk && c < nbp1) ? gbase[(size_t)r * nbp1 + c] : 0;
    }
    __syncthreads();
    for (int dy = ty; dy < TD; dy += 8) {
        int r = c0 + dy, c = r0 + tx;       // row = bucket, col = blk
        if (r < nbp1 && c < nblk)
            gbaseT[(size_t)r * nblk + c] = tile[tx][dy];
    }
}

// ---- Phase 2: one 1024-thread block per bucket. Zero-atomic gather of the
// bucket's edges into LDS (len scan -> dests -> parallel copy), then count
// per node, scan, write packed rowptr + dinv, classify nodes into degree
// lists, place colidx. ----
// rowptr[g] = (edge_base << 8) | min(deg,255) ; colidx entry = src_byte_off.
__global__ __launch_bounds__(1024) void k_bfill(const unsigned* __restrict__ binned,
                                                const int* __restrict__ gbaseT,
                                                int nblk, int nb,
                                                int* __restrict__ rowptr,
                                                int* __restrict__ colidx,
                                                float* __restrict__ dinv,
                                                int* __restrict__ list0,
                                                int* __restrict__ list1,
                                                int* __restrict__ clscnt, int n) {
    __shared__ unsigned pedges[PMAX];   // 46 KB: packed edge values
    __shared__ int segarr[2048];        // lens, then exclusive prefix (dest)
    __shared__ int stmp[1024];
    __shared__ int cnt[BSZ];
    __shared__ int nbase[BSZ];
    __shared__ int lcnt[2], lcur[2], lbase[2];
    const int b = blockIdx.x;
    const int t = threadIdx.x;
    const int* rowS = gbaseT + (size_t)b * nblk;        // s0 per blk (coalesced)
    const int* rowE = gbaseT + (size_t)(b + 1) * nblk;  // s1 per blk (coalesced)
    for (int i = t; i < BSZ; i += 1024) cnt[i] = 0;
    if (t < 2) lcnt[t] = 0;
    // load lens (strided, coalesced) + ebeg partial
    int eb = 0;
    {
        int l0 = 0, l1 = 0;
        if (t < nblk)        { int s0 = rowS[t];        l0 = rowE[t] - s0;        eb += s0; }
        if (t + 1024 < nblk) { int s0 = rowS[t + 1024]; l1 = rowE[t + 1024] - s0; eb += s0; }
        segarr[t] = l0;
        segarr[t + 1024] = l1;
    }
    // ebeg reduction
    stmp[t] = eb;
    __syncthreads();
    for (int off = 512; off; off >>= 1) {
        if (t < off) stmp[t] += stmp[t + off];
        __syncthreads();
    }
    const int ebeg = stmp[0];
    __syncthreads();
    // pairwise exclusive scan over segarr[2048]: thread t owns 2t, 2t+1
    const int a0 = segarr[2 * t];
    const int a1 = segarr[2 * t + 1];
    const int ps = a0 + a1;
    stmp[t] = ps;
    __syncthreads();
    for (int off = 1; off < 1024; off <<= 1) {
        int u = (t >= off) ? stmp[t - off] : 0;
        __syncthreads();
        stmp[t] += u;
        __syncthreads();
    }
    const int ecnt = min(stmp[1023], PMAX);   // bucket total
    const int exp2_ = stmp[t] - ps;
    segarr[2 * t] = exp2_;
    segarr[2 * t + 1] = exp2_ + a0;
    __syncthreads();
    // parallel segment copy (no atomics; dests precomputed)
    for (int blk = t; blk < nblk; blk += 1024) {
        const int s0 = rowS[blk];
        const int c = rowE[blk] - s0;
        const int pos = segarr[blk];
        const unsigned* bp = binned + (size_t)blk * BIN_CH + s0;
        for (int k = 0; k < c; ++k) {
            const int d = pos + k;
            if (d < PMAX) pedges[d] = bp[k];
        }
    }
    __syncthreads();
    // pass A: per-node counts (pure LDS)
    for (int j = t; j < ecnt; j += 1024)
        atomicAdd(&cnt[pedges[j] >> 17], 1);
    __syncthreads();
    // node scan (512 nodes; threads 0-255 own 2 nodes each)
    const int c0 = (t < 256) ? cnt[2 * t] : 0;
    const int c1 = (t < 256) ? cnt[2 * t + 1] : 0;
    const int s2 = c0 + c1;
    stmp[t] = s2;
    __syncthreads();
    for (int off = 1; off < 256; off <<= 1) {
        int u = (t >= off && t < 256) ? stmp[t - off] : 0;
        __syncthreads();
        if (t < 256) stmp[t] += u;
        __syncthreads();
    }
    if (t < 256) {
        const int ex = stmp[t] - s2;
        nbase[2 * t] = ex;
        nbase[2 * t + 1] = ex + c0;
    }
    __syncthreads();
    const int gb9 = b << SHIFT;
    // loop1: rowptr + dinv + class count
    for (int j = t; j < BSZ; j += 1024) {
        const int g = gb9 + j;
        if (g < n) {
            const int dg = cnt[j];
            rowptr[g] = (int)(((unsigned)(ebeg + nbase[j]) << 8) |
                              (unsigned)min(dg, 255));
            dinv[g] = rsqrtf((float)dg + 1.0f);
            atomicAdd(&lcnt[dg <= 16 ? 0 : 1], 1);
        }
    }
    __syncthreads();
    if (t < 2) {
        lbase[t] = atomicAdd(&clscnt[t], lcnt[t]);
        lcur[t] = 0;
    }
    __syncthreads();
    // loop2: list placement + convert cnt -> cursor
    for (int j = t; j < BSZ; j += 1024) {
        const int g = gb9 + j;
        if (g < n) {
            const int dg = cnt[j];
            const int c = dg <= 16 ? 0 : 1;
            const int pos = atomicAdd(&lcur[c], 1);
            (c ? list1 : list0)[lbase[c] + pos] = g;
        }
        cnt[j] = nbase[j];   // becomes local cursor
    }
    __syncthreads();
    // pass B: place (LDS read; colidx region is bucket-private)
    for (int j = t; j < ecnt; j += 1024) {
        const unsigned e = pedges[j];
        const int lo = (int)(e >> 17);
        const int off = atomicAdd(&cnt[lo], 1);
        colidx[ebeg + off] = (int)((e & 0x1FFFFu) << 7);  // byte offset of src row
    }
}

// MFMA GEMM: C16[n,64] = fp16( (A[n,K] @ W[K,64]) * dinv[row] ).
// Block = 256 threads = 4 waves; wave w computes rows rb+w*16..+15, all 64 cols.
template <int K, bool A_FP32>
__global__ __launch_bounds__(256) void k_gemm_mfma(const void* __restrict__ Av,
                                                   const float* __restrict__ W,
                                                   const float* __restrict__ dinv,
                                                   __half* __restrict__ C, int n) {
    constexpr int KP = K + 8;  // padded LDS row stride in halves (16B aligned)
    __shared__ _Float16 Wt[64 * KP];
    const int tid = threadIdx.x;
    for (int i = tid; i < K * 64; i += 256) {
        int k = i >> 6, c = i & 63;
        Wt[c * KP + k] = (_Float16)W[i];
    }
    __syncthreads();

    const int lane = tid & 63;
    const int wv = tid >> 6;
    const int r16 = lane & 15;
    const int kq = lane >> 4;                       // 0..3
    const int rb = blockIdx.x * 64 + wv * 16;
    const int arow = min(rb + r16, n - 1);          // clamped A row for this lane

    f32x4 acc[4] = {{0.f,0.f,0.f,0.f},{0.f,0.f,0.f,0.f},
                    {0.f,0.f,0.f,0.f},{0.f,0.f,0.f,0.f}};

#pragma unroll
    for (int kk = 0; kk < K; kk += 32) {
        f16x8 a;
        if (A_FP32) {
            const float* Ap = (const float*)Av + (size_t)arow * K + kk + kq * 8;
            float4 f0 = *reinterpret_cast<const float4*>(Ap);
            float4 f1 = *reinterpret_cast<const float4*>(Ap + 4);
            a[0] = (_Float16)f0.x; a[1] = (_Float16)f0.y;
            a[2] = (_Float16)f0.z; a[3] = (_Float16)f0.w;
            a[4] = (_Float16)f1.x; a[5] = (_Float16)f1.y;
            a[6] = (_Float16)f1.z; a[7] = (_Float16)f1.w;
        } else {
            const _Float16* Ap = (const _Float16*)Av + (size_t)arow * K + kk + kq * 8;
            a = *reinterpret_cast<const f16x8*>(Ap);
        }
#pragma unroll
        for (int nt = 0; nt < 4; ++nt) {
            f16x8 b = *reinterpret_cast<const f16x8*>(&Wt[(nt * 16 + r16) * KP + kk + kq * 8]);
            acc[nt] = __builtin_amdgcn_mfma_f32_16x16x32_f16(a, b, acc[nt], 0, 0, 0);
        }
    }

#pragma unroll
    for (int r = 0; r < 4; ++r) {
        const int row = rb + kq * 4 + r;
        if (row < n) {
            const float di = dinv[row];
#pragma unroll
            for (int nt = 0; nt < 4; ++nt)
                C[((size_t)row << 6) + nt * 16 + r16] = __float2half(acc[nt][r] * di);
        }
    }
}

// Accumulate 8 fp16 (one uint4) into acc[8] via v_dot2_f32_f16: one VALU op per
// value (convert+add fused, fp32 accumulate). Masks (1,0)/(0,1) keep channels
// separate; exact 1.0-multiply => bit-identical to cvt+add.
__device__ __forceinline__ void dotu4(float acc[8], uint4 u, f16x2 pl, f16x2 ph) {
    union { uint4 u4; f16x2 h[4]; } v;
    v.u4 = u;
    acc[0] = __builtin_amdgcn_fdot2(v.h[0], pl, acc[0], false);
    acc[1] = __builtin_amdgcn_fdot2(v.h[0], ph, acc[1], false);
    acc[2] = __builtin_amdgcn_fdot2(v.h[1], pl, acc[2], false);
    acc[3] = __builtin_amdgcn_fdot2(v.h[1], ph, acc[3], false);
    acc[4] = __builtin_amdgcn_fdot2(v.h[2], pl, acc[4], false);
    acc[5] = __builtin_amdgcn_fdot2(v.h[2], ph, acc[5], false);
    acc[6] = __builtin_amdgcn_fdot2(v.h[3], pl, acc[6], false);
    acc[7] = __builtin_amdgcn_fdot2(v.h[3], ph, acc[7], false);
}

// Fold partial sums across the 8 groups: after this every lane holds the full
// sums for its channel-slice p.
__device__ __forceinline__ void fold8(float acc[8]) {
#pragma unroll
    for (int m = 8; m <= 32; m <<= 1) {
#pragma unroll
        for (int j = 0; j < 8; ++j)
            acc[j] += __shfl_xor(acc[j], m, 64);
    }
}

// 2-node pipelined gather, 4 slots/node + deg>32 tails (R20/R14 proven shape).
__device__ __forceinline__ void gather_pair(const char* __restrict__ hsb,
                                            const int* __restrict__ colidx,
                                            unsigned pk0, unsigned pk1,
                                            int g, int p, unsigned dum,
                                            float acc0[8], float acc1[8]) {
    const f16x2 pl = {(_Float16)1.0f, (_Float16)0.0f};
    const f16x2 ph = {(_Float16)0.0f, (_Float16)1.0f};
    const int beg0 = (int)(pk0 >> 8), deg0 = (int)(pk0 & 255u);
    const int beg1 = (int)(pk1 >> 8), deg1 = (int)(pk1 & 255u);
    const int t0 = deg0 - g, t1 = deg1 - g;   // slot k valid iff 8*k < t
    const unsigned poff = (unsigned)(p << 4);
    const unsigned dumo = dum + poff;
    const int ia = beg0 + g;
    const int ib = beg1 + g;
    unsigned a0 = (unsigned)colidx[ia]      + poff;
    unsigned a1 = (unsigned)colidx[ia + 8]  + poff;
    unsigned a2 = (unsigned)colidx[ia + 16] + poff;
    unsigned a3 = (unsigned)colidx[ia + 24] + poff;
    unsigned b0 = (unsigned)colidx[ib]      + poff;
    unsigned b1 = (unsigned)colidx[ib + 8]  + poff;
    unsigned b2 = (unsigned)colidx[ib + 16] + poff;
    unsigned b3 = (unsigned)colidx[ib + 24] + poff;
    unsigned oa0 = (0  < t0) ? a0 : dumo;
    unsigned oa1 = (8  < t0) ? a1 : dumo;
    unsigned oa2 = (16 < t0) ? a2 : dumo;
    unsigned oa3 = (24 < t0) ? a3 : dumo;
    unsigned ob0 = (0  < t1) ? b0 : dumo;
    unsigned ob1 = (8  < t1) ? b1 : dumo;
    unsigned ob2 = (16 < t1) ? b2 : dumo;
    unsigned ob3 = (24 < t1) ? b3 : dumo;
    uint4 ua0 = *reinterpret_cast<const uint4*>(hsb + oa0);
    uint4 ua1 = *reinterpret_cast<const uint4*>(hsb + oa1);
    uint4 ua2 = *reinterpret_cast<const uint4*>(hsb + oa2);
    uint4 ua3 = *reinterpret_cast<const uint4*>(hsb + oa3);
    uint4 ub0 = *reinterpret_cast<const uint4*>(hsb + ob0);
    uint4 ub1 = *reinterpret_cast<const uint4*>(hsb + ob1);
    uint4 ub2 = *reinterpret_cast<const uint4*>(hsb + ob2);
    uint4 ub3 = *reinterpret_cast<const uint4*>(hsb + ob3);
    dotu4(acc0, ua0, pl, ph);
    dotu4(acc0, ua1, pl, ph);
    dotu4(acc0, ua2, pl, ph);
    dotu4(acc0, ua3, pl, ph);
    dotu4(acc1, ub0, pl, ph);
    dotu4(acc1, ub1, pl, ph);
    dotu4(acc1, ub2, pl, ph);
    dotu4(acc1, ub3, pl, ph);
    // rare tails (deg > 32), wave-uniform, after the main dots
    const int ns0 = (deg0 + 7) >> 3;
    for (int k = 4; k < ns0; k += 4) {
        const int ik = beg0 + 8 * k + g;
        unsigned c0 = (unsigned)colidx[ik]      + poff;
        unsigned c1 = (unsigned)colidx[ik + 8]  + poff;
        unsigned c2 = (unsigned)colidx[ik + 16] + poff;
        unsigned c3 = (unsigned)colidx[ik + 24] + poff;
        const int kb = 8 * k;
        uint4 u0 = *reinterpret_cast<const uint4*>(hsb + ((kb      < t0) ? c0 : dumo));
        uint4 u1 = *reinterpret_cast<const uint4*>(hsb + ((kb + 8  < t0) ? c1 : dumo));
        uint4 u2 = *reinterpret_cast<const uint4*>(hsb + ((kb + 16 < t0) ? c2 : dumo));
        uint4 u3 = *reinterpret_cast<const uint4*>(hsb + ((kb + 24 < t0) ? c3 : dumo));
        dotu4(acc0, u0, pl, ph);
        dotu4(acc0, u1, pl, ph);
        dotu4(acc0, u2, pl, ph);
        dotu4(acc0, u3, pl, ph);
    }
    const int ns1 = (deg1 + 7) >> 3;
    for (int k = 4; k < ns1; k += 4) {
        const int ik = beg1 + 8 * k + g;
        unsigned c0 = (unsigned)colidx[ik]      + poff;
        unsigned c1 = (unsigned)colidx[ik + 8]  + poff;
        unsigned c2 = (unsigned)colidx[ik + 16] + poff;
        unsigned c3 = (unsigned)colidx[ik + 24] + poff;
        const int kb = 8 * k;
        uint4 u0 = *reinterpret_cast<const uint4*>(hsb + ((kb      < t1) ? c0 : dumo));
        uint4 u1 = *reinterpret_cast<const uint4*>(hsb + ((kb + 8  < t1) ? c1 : dumo));
        uint4 u2 = *reinterpret_cast<const uint4*>(hsb + ((kb + 16 < t1) ? c2 : dumo));
        uint4 u3 = *reinterpret_cast<const uint4*>(hsb + ((kb + 24 < t1) ? c3 : dumo));
        dotu4(acc1, u0, pl, ph);
        dotu4(acc1, u1, pl, ph);
        dotu4(acc1, u2, pl, ph);
        dotu4(acc1, u3, pl, ph);
    }
    fold8(acc0);
    fold8(acc1);
}

// 4-node x 2-slot gather for deg<=16 nodes: 8 colidx + 8 gathers issued
// back-to-back (16 VMEM, same schedule shape as gather_pair) serving 4 nodes.
// No tails possible.
__device__ __forceinline__ void gather_quad2(const char* __restrict__ hsb,
                                             const int* __restrict__ colidx,
                                             unsigned pk0, unsigned pk1,
                                             unsigned pk2, unsigned pk3,
                                             int g, int p, unsigned dum,
                                             float a0[8], float a1[8],
                                             float a2[8], float a3[8]) {
    const f16x2 pl = {(_Float16)1.0f, (_Float16)0.0f};
    const f16x2 ph = {(_Float16)0.0f, (_Float16)1.0f};
    const int beg0 = (int)(pk0 >> 8), deg0 = (int)(pk0 & 255u);
    const int beg1 = (int)(pk1 >> 8), deg1 = (int)(pk1 & 255u);
    const int beg2 = (int)(pk2 >> 8), deg2 = (int)(pk2 & 255u);
    const int beg3 = (int)(pk3 >> 8), deg3 = (int)(pk3 & 255u);
    const int t0 = deg0 - g, t1 = deg1 - g, t2 = deg2 - g, t3 = deg3 - g;
    const unsigned poff = (unsigned)(p << 4);
    const unsigned dumo = dum + poff;
    const int ia = beg0 + g, ib = beg1 + g, ic = beg2 + g, id = beg3 + g;
    unsigned a_0 = (unsigned)colidx[ia]     + poff;
    unsigned a_1 = (unsigned)colidx[ia + 8] + poff;
    unsigned b_0 = (unsigned)colidx[ib]     + poff;
    unsigned b_1 = (unsigned)colidx[ib + 8] + poff;
    unsigned c_0 = (unsigned)colidx[ic]     + poff;
    unsigned c_1 = (unsigned)colidx[ic + 8] + poff;
    unsigned d_0 = (unsigned)colidx[id]     + poff;
    unsigned d_1 = (unsigned)colidx[id + 8] + poff;
    unsigned oa0 = (0 < t0) ? a_0 : dumo;
    unsigned oa1 = (8 < t0) ? a_1 : dumo;
    unsigned ob0 = (0 < t1) ? b_0 : dumo;
    unsigned ob1 = (8 < t1) ? b_1 : dumo;
    unsigned oc0 = (0 < t2) ? c_0 : dumo;
    unsigned oc1 = (8 < t2) ? c_1 : dumo;
    unsigned od0 = (0 < t3) ? d_0 : dumo;
    unsigned od1 = (8 < t3) ? d_1 : dumo;
    uint4 ua0 = *reinterpret_cast<const uint4*>(hsb + oa0);
    uint4 ua1 = *reinterpret_cast<const uint4*>(hsb + oa1);
    uint4 ub0 = *reinterpret_cast<const uint4*>(hsb + ob0);
    uint4 ub1 = *reinterpret_cast<const uint4*>(hsb + ob1);
    uint4 uc0 = *reinterpret_cast<const uint4*>(hsb + oc0);
    uint4 uc1 = *reinterpret_cast<const uint4*>(hsb + oc1);
    uint4 ud0 = *reinterpret_cast<const uint4*>(hsb + od0);
    uint4 ud1 = *reinterpret_cast<const uint4*>(hsb + od1);
    dotu4(a0, ua0, pl, ph);
    dotu4(a0, ua1, pl, ph);
    dotu4(a1, ub0, pl, ph);
    dotu4(a1, ub1, pl, ph);
    dotu4(a2, uc0, pl, ph);
    dotu4(a2, uc1, pl, ph);
    dotu4(a3, ud0, pl, ph);
    dotu4(a3, ud1, pl, ph);
    fold8(a0);
    fold8(a1);
    fold8(a2);
    fold8(a3);
}

// Select this lane's node accumulator (nsel in 0..3).
__device__ __forceinline__ void sel4(float a[8], int nsel, const float a0[8],
                                     const float a1[8], const float a2[8],
                                     const float a3[8]) {
#pragma unroll
    for (int j = 0; j < 8; ++j) {
        float x01 = (nsel & 1) ? a1[j] : a0[j];
        float x23 = (nsel & 1) ? a3[j] : a2[j];
        a[j] = (nsel & 2) ? x23 : x01;
    }
}

// Epilogue helper: relu+bias -> fp16x8 store for one node row.
__device__ __forceinline__ void store_relu(float a[8], float di,
                                           const float* __restrict__ b, int p,
                                           __half* __restrict__ out, int row) {
    float4 b0 = *reinterpret_cast<const float4*>(b + (p << 3));
    float4 b1 = *reinterpret_cast<const float4*>(b + (p << 3) + 4);
    __half2 h0 = __halves2half2(__float2half(fmaxf(fmaf(a[0], di, b0.x), 0.f)),
                                __float2half(fmaxf(fmaf(a[1], di, b0.y), 0.f)));
    __half2 h1 = __halves2half2(__float2half(fmaxf(fmaf(a[2], di, b0.z), 0.f)),
                                __float2half(fmaxf(fmaf(a[3], di, b0.w), 0.f)));
    __half2 h2 = __halves2half2(__float2half(fmaxf(fmaf(a[4], di, b1.x), 0.f)),
                                __float2half(fmaxf(fmaf(a[5], di, b1.y), 0.f)));
    __half2 h3 = __halves2half2(__float2half(fmaxf(fmaf(a[6], di, b1.z), 0.f)),
                                __float2half(fmaxf(fmaf(a[7], di, b1.w), 0.f)));
    uint4 u;
    u.x = *reinterpret_cast<unsigned*>(&h0);
    u.y = *reinterpret_cast<unsigned*>(&h1);
    u.z = *reinterpret_cast<unsigned*>(&h2);
    u.w = *reinterpret_cast<unsigned*>(&h3);
    *reinterpret_cast<uint4*>(out + ((size_t)row << 6) + (p << 3)) = u;
}

// Epilogue helper: relu+bias -> dot with Wl (one node scalar partial).
__device__ __forceinline__ float head_val(float a[8], float di,
                                          const float* __restrict__ b2,
                                          const float* __restrict__ Wl, int p) {
    float4 b0 = *reinterpret_cast<const float4*>(b2 + (p << 3));
    float4 b1 = *reinterpret_cast<const float4*>(b2 + (p << 3) + 4);
    float4 w0 = *reinterpret_cast<const float4*>(Wl + (p << 3));
    float4 w1 = *reinterpret_cast<const float4*>(Wl + (p << 3) + 4);
    float v = fmaxf(fmaf(a[0], di, b0.x), 0.f) * w0.x
            + fmaxf(fmaf(a[1], di, b0.y), 0.f) * w0.y
            + fmaxf(fmaf(a[2], di, b0.z), 0.f) * w0.z
            + fmaxf(fmaf(a[3], di, b0.w), 0.f) * w0.w
            + fmaxf(fmaf(a[4], di, b1.x), 0.f) * w1.x
            + fmaxf(fmaf(a[5], di, b1.y), 0.f) * w1.y
            + fmaxf(fmaf(a[6], di, b1.z), 0.f) * w1.z
            + fmaxf(fmaf(a[7], di, b1.w), 0.f) * w1.w;
    v += __shfl_xor(v, 1, 64);
    v += __shfl_xor(v, 2, 64);
    v += __shfl_xor(v, 4, 64);
    return v;
}

// conv1 agg, class0 (deg<=16): 4 nodes/wave x 2 slots.
__global__ __launch_bounds__(256) void k_agg_relu_c0(const __half* __restrict__ hs,
                                                     const int* __restrict__ rowptr,
                                                     const int* __restrict__ colidx,
                                                     const int* __restrict__ list,
                                                     const int* __restrict__ clscnt,
                                                     const float* __restrict__ dinv,
                                                     const float* __restrict__ b,
                                                     __half* __restrict__ out, int n) {
    const int cntc = clscnt[0];
    const int i0 = (blockIdx.x * 4 + (threadIdx.x >> 6)) * 4;
    if (i0 >= cntc) return;
    const int lane = threadIdx.x & 63;
    const int g = lane >> 3, p = lane & 7;
    const int nsel = g & 3;
    const int last = cntc - 1;
    const int id0 = list[min(i0,     last)];
    const int id1 = list[min(i0 + 1, last)];
    const int id2 = list[min(i0 + 2, last)];
    const int id3 = list[min(i0 + 3, last)];
    const int idsel = (nsel & 1) ? ((nsel & 2) ? id3 : id1)
                                 : ((nsel & 2) ? id2 : id0);
    const bool valid = (i0 + nsel) < cntc;
    const unsigned pk0 = (unsigned)rowptr[id0];
    const unsigned pk1 = (unsigned)rowptr[id1];
    const unsigned pk2 = (unsigned)rowptr[id2];
    const unsigned pk3 = (unsigned)rowptr[id3];
    uint4 su = *reinterpret_cast<const uint4*>(hs + ((size_t)idsel << 6) + (p << 3));
    const float di = dinv[idsel];
    float a0[8] = {}, a1[8] = {}, a2[8] = {}, a3[8] = {};
    gather_quad2((const char*)hs, colidx, pk0, pk1, pk2, pk3, g, p,
                 (unsigned)n << 7, a0, a1, a2, a3);
    if (lane < 32 && valid) {
        const f16x2 pl = {(_Float16)1.0f, (_Float16)0.0f};
        const f16x2 ph = {(_Float16)0.0f, (_Float16)1.0f};
        float a[8];
        sel4(a, nsel, a0, a1, a2, a3);
        dotu4(a, su, pl, ph);
        store_relu(a, di, b, p, out, idsel);
    }
}

// conv1 agg, class1 (deg>16): 2 nodes/wave x 4 slots + tails (R20 shape).
__global__ __launch_bounds__(256) void k_agg_relu_c1(const __half* __restrict__ hs,
                                                     const int* __restrict__ rowptr,
                                                     const int* __restrict__ colidx,
                                                     const int* __restrict__ list,
                                                     const int* __restrict__ clscnt,
                                                     const float* __restrict__ dinv,
                                                     const float* __restrict__ b,
                                                     __half* __restrict__ out, int n) {
    const int cntc = clscnt[1];
    const int i0 = (blockIdx.x * 4 + (threadIdx.x >> 6)) * 2;
    if (i0 >= cntc) return;
    const int lane = threadIdx.x & 63;
    const int g = lane >> 3, p = lane & 7;
    const int last = cntc - 1;
    const int id0 = list[min(i0,     last)];
    const int id1 = list[min(i0 + 1, last)];
    const int iw = (lane & 8) ? id1 : id0;
    const bool valid = (i0 + ((lane >> 3) & 1)) < cntc;
    const unsigned pk0 = (unsigned)rowptr[id0];
    const unsigned pk1 = (unsigned)rowptr[id1];
    uint4 su = *reinterpret_cast<const uint4*>(hs + ((size_t)iw << 6) + (p << 3));
    const float di = dinv[iw];
    float acc0[8] = {}, acc1[8] = {};
    gather_pair((const char*)hs, colidx, pk0, pk1, g, p, (unsigned)n << 7,
                acc0, acc1);
    if (lane < 16 && valid) {
        const f16x2 pl = {(_Float16)1.0f, (_Float16)0.0f};
        const f16x2 ph = {(_Float16)0.0f, (_Float16)1.0f};
        float a[8];
#pragma unroll
        for (int j = 0; j < 8; ++j) a[j] = (lane & 8) ? acc1[j] : acc0[j];
        dotu4(a, su, pl, ph);
        store_relu(a, di, b, p, out, iw);
    }
}

// conv2+head agg, class0: 4 nodes/wave x 2 slots.
__global__ __launch_bounds__(256) void k_agg_head_c0(const __half* __restrict__ hs,
                                                     const int* __restrict__ rowptr,
                                                     const int* __restrict__ colidx,
                                                     const int* __restrict__ list,
                                                     const int* __restrict__ clscnt,
                                                     const float* __restrict__ dinv,
                                                     const float* __restrict__ b2,
                                                     const float* __restrict__ Wl,
                                                     const float* __restrict__ bl,
                                                     float* __restrict__ out, int n) {
    const int cntc = clscnt[0];
    const int i0 = (blockIdx.x * 4 + (threadIdx.x >> 6)) * 4;
    if (i0 >= cntc) return;
    const int lane = threadIdx.x & 63;
    const int g = lane >> 3, p = lane & 7;
    const int nsel = g & 3;
    const int last = cntc - 1;
    const int id0 = list[min(i0,     last)];
    const int id1 = list[min(i0 + 1, last)];
    const int id2 = list[min(i0 + 2, last)];
    const int id3 = list[min(i0 + 3, last)];
    const int idsel = (nsel & 1) ? ((nsel & 2) ? id3 : id1)
                                 : ((nsel & 2) ? id2 : id0);
    const unsigned pk0 = (unsigned)rowptr[id0];
    const unsigned pk1 = (unsigned)rowptr[id1];
    const unsigned pk2 = (unsigned)rowptr[id2];
    const unsigned pk3 = (unsigned)rowptr[id3];
    uint4 su = *reinterpret_cast<const uint4*>(hs + ((size_t)idsel << 6) + (p << 3));
    const float di = dinv[idsel];
    float a0[8] = {}, a1[8] = {}, a2[8] = {}, a3[8] = {};
    gather_quad2((const char*)hs, colidx, pk0, pk1, pk2, pk3, g, p,
                 (unsigned)n << 7, a0, a1, a2, a3);
    const f16x2 pl = {(_Float16)1.0f, (_Float16)0.0f};
    const f16x2 ph = {(_Float16)0.0f, (_Float16)1.0f};
    float a[8];
    sel4(a, nsel, a0, a1, a2, a3);
    dotu4(a, su, pl, ph);
    const float v = head_val(a, di, b2, Wl, p);
    if (p == 0 && g < 4 && (i0 + g) < cntc) out[idsel] = v + bl[0];
}

// conv2+head agg, class1: 2 nodes/wave x 4 slots + tails.
__global__ __launch_bounds__(256) void k_agg_head_c1(const __half* __restrict__ hs,
                                                     const int* __restrict__ rowptr,
                                                     const int* __restrict__ colidx,
                                                     const int* __restrict__ list,
                                                     const int* __restrict__ clscnt,
                                                     const float* __restrict__ dinv,
                                                     const float* __restrict__ b2,
                                                     const float* __restrict__ Wl,
                                                     const float* __restrict__ bl,
                                                     float* __restrict__ out, int n) {
    const int cntc = clscnt[1];
    const int i0 = (blockIdx.x * 4 + (threadIdx.x >> 6)) * 2;
    if (i0 >= cntc) return;
    const int lane = threadIdx.x & 63;
    const int g = lane >> 3, p = lane & 7;
    const int last = cntc - 1;
    const int id0 = list[min(i0,     last)];
    const int id1 = list[min(i0 + 1, last)];
    const int iw = (lane & 8) ? id1 : id0;
    const unsigned pk0 = (unsigned)rowptr[id0];
    const unsigned pk1 = (unsigned)rowptr[id1];
    uint4 su = *reinterpret_cast<const uint4*>(hs + ((size_t)iw << 6) + (p << 3));
    const float di = dinv[iw];
    float acc0[8] = {}, acc1[8] = {};
    gather_pair((const char*)hs, colidx, pk0, pk1, g, p, (unsigned)n << 7,
                acc0, acc1);
    const f16x2 pl = {(_Float16)1.0f, (_Float16)0.0f};
    const f16x2 ph = {(_Float16)0.0f, (_Float16)1.0f};
    float a[8];
#pragma unroll
    for (int j = 0; j < 8; ++j) a[j] = (lane & 8) ? acc1[j] : acc0[j];
    dotu4(a, su, pl, ph);
    const float v = head_val(a, di, b2, Wl, p);
    if (lane == 0) out[id0] = v + bl[0];
    if (lane == 8 && i0 + 1 < cntc) out[id1] = v + bl[0];
}

extern "C" void kernel_launch(void* const* d_in, const int* in_sizes, int n_in,
                              void* d_out, int out_size, void* d_ws, size_t ws_size,
                              hipStream_t stream) {
    const float* x  = (const float*)d_in[0];
    const int*   ei = (const int*)d_in[1];
    const float* W1 = (const float*)d_in[2];
    const float* b1 = (const float*)d_in[3];
    const float* W2 = (const float*)d_in[4];
    const float* b2 = (const float*)d_in[5];
    const float* Wl = (const float*)d_in[6];
    const float* bl = (const float*)d_in[7];
    float* out = (float*)d_out;

    const int n = in_sizes[0] / 128;   // 100000
    const int E = in_sizes[1] / 2;     // 1600000
    const int* src = ei;
    const int* dst = ei + E;
    const int nb = (n + BSZ - 1) >> SHIFT;          // 196 buckets
    const int nblk = (E + BIN_CH - 1) / BIN_CH;     // 1563 k_bin blocks

    char* ws = (char*)d_ws;
    size_t o = 0;
    auto alloc = [&](size_t bytes) {
        void* p = ws + o;
        o = (o + bytes + 255) & ~(size_t)255;
        return p;
    };
    float* dinv    = (float*)alloc((size_t)n * 4);
    int*   rowptr  = (int*)  alloc((size_t)(n + 1) * 4);
    int*   colidx  = (int*)  alloc(((size_t)E + 64) * 4);        // +slack for unrolled reads
    int*   gbase   = (int*)  alloc((size_t)nblk * (nb + 1) * 4); // per-block bucket offsets
    int*   gbaseT  = (int*)  alloc((size_t)(nb + 1) * nblk * 4); // transposed
    int*   list0   = (int*)  alloc((size_t)n * 4);               // deg<=16 nodes
    int*   list1   = (int*)  alloc((size_t)n * 4);               // deg>16 nodes
    int*   clscnt  = (int*)  alloc(256);                         // [2] class counts
    __half* hs     = (__half*)alloc((size_t)(n + 1) * 64 * 2);   // +1 zeroed dummy row
    __half* bufA   = (__half*)alloc((size_t)n * 64 * 2);         // fp16 relu output
    unsigned* binned = (unsigned*)alloc(((size_t)nblk * BIN_CH) * 4);  // block-major

    // ---- CSR build (block-private counting sort; line-private stores only)
    k_bin<<<nblk, 256, 0, stream>>>(src, dst, binned, gbase, hs, clscnt, n, nb, E);
    const int ctiles = (nb + 1 + TD - 1) / TD;
    const int rtiles = (nblk + TD - 1) / TD;
    k_xpose<<<ctiles * rtiles, 256, 0, stream>>>(gbase, gbaseT, nblk, nb + 1);
    k_bfill<<<nb, 1024, 0, stream>>>(binned, gbaseT, nblk, nb, rowptr, colidx,
                                     dinv, list0, list1, clscnt, n);

    // ---- conv1 ----
    k_gemm_mfma<128, true><<<(n + 63) / 64, 256, 0, stream>>>(x, W1, dinv, hs, n);
    k_agg_relu_c0<<<(n + 15) / 16, 256, 0, stream>>>(hs, rowptr, colidx, list0,
                                                     clscnt, dinv, b1, bufA, n);
    k_agg_relu_c1<<<(n + 7) / 8, 256, 0, stream>>>(hs, rowptr, colidx, list1,
                                                   clscnt, dinv, b1, bufA, n);

    // ---- conv2 + head ----
    k_gemm_mfma<64, false><<<(n + 63) / 64, 256, 0, stream>>>(bufA, W2, dinv, hs, n);
    k_agg_head_c0<<<(n + 15) / 16, 256, 0, stream>>>(hs, rowptr, colidx, list0,
                                                     clscnt, dinv, b2, Wl, bl,
                                                     out, n);
    k_agg_head_c1<<<(n + 7) / 8, 256, 0, stream>>>(hs, rowptr, colidx, list1,
                                                   clscnt, dinv, b2, Wl, bl,
                                                   out, n);
}

// Round 12
// 135.798 us; speedup vs baseline: 1.0894x; 1.0894x over previous
//
#include <hip/hip_runtime.h>
#include <hip/hip_fp16.h>

// GCNRegressor: x[n,128] --GCNConv(W1)--> relu --GCNConv(W2)--> relu --@Wl+bl--> out[n]
// n=100000, E=1600000, IN=128, HID=64.
// R1-R10: CSR+gather, counting sort, fp16 features, MFMA GEMMs: 2913 -> 171 us.
// R11: 8-rows-per-VMEM gather (wave = 8 groups x 8 lanes, uint4/lane): 41.8us agg.
// R12/R13: LESSON: agg is LATENCY-bound; no branches between issue & consume.
// R14: 2 nodes/wave pipelined (16 VMEM in flight): 162 -> 148.7.
// R15: fixed 32-slot cfix aggs were ~12us/agg FASTER (retro arithmetic), but
//      its CSR build was broken (k_bin 40us): net 156.9.
// R16/R17: RULE: every 64B line of a store stream filled by ONE block.
// R18/R19: block-major binned + values-to-LDS + transposed gbase.
// R20: zero-atomic scans + 1024-thr k_bfill: 133.2. BEST.
// R21: 4-node agg WITH rowptr chain: neutral -- chain depth, not slot count,
//      is the cost. R22: list indirection (4-level chain): 147.9 REGRESSION.
// R23: R20's build producing R15's fixed-slot layout: cfix[node*32+slot] with
//      dummy baked in (chain 3 -> 2 levels, zero masking VALU), per-bucket
//      ovf for deg>32, consumed by R15's 4-node/wave agg (32 VMEM in flight).

#define SHIFT 9
#define BSZ   (1 << SHIFT)     // 512 nodes per bucket
#define NBMAX 256              // >= nb = 196
#define BIN_CH 1024            // edges per k_bin block (private region)
#define PMAX  11776            // bucket edge capacity (mean 8163, +40 sigma)
#define OCAP  1024             // per-bucket overflow capacity (deg>32 edges)

using f16x8 = __attribute__((ext_vector_type(8))) _Float16;
using f16x2 = __attribute__((ext_vector_type(2))) _Float16;
using f32x4 = __attribute__((ext_vector_type(4))) float;

// ---- Phase 1: per-block counting sort into private binned region ----
// binned[blk*BIN_CH + ex[bucket] ...] sorted by bucket; gbase[blk*(nb+1)+i] =
// exclusive prefix of this block's bucket counts (row i=nb = chunk total).
// pack: src(17b) | local_node(9b)<<17. Block 0 also zeroes the dummy hs row.
__global__ __launch_bounds__(256) void k_bin(const int* __restrict__ src,
                                             const int* __restrict__ dst,
                                             unsigned* __restrict__ binned,
                                             int* __restrict__ gbase,
                                             __half* __restrict__ hs,
                                             int n, int nb, int E) {
    if (blockIdx.x == 0 && threadIdx.x < 8) {
        uint4 z = {0u, 0u, 0u, 0u};
        reinterpret_cast<uint4*>(hs + ((size_t)n << 6))[threadIdx.x] = z;
    }
    __shared__ int h[NBMAX];
    __shared__ int ex[NBMAX + 1];
    __shared__ int cur[NBMAX];
    __shared__ int stmp[256];
    const int t = threadIdx.x;
    const int blk = blockIdx.x;
    const int beg = blk * BIN_CH;
    for (int i = t; i < NBMAX; i += 256) h[i] = 0;
    __syncthreads();
    const int e4 = beg + t * 4;
    const bool act = e4 < E;               // E % 4 == 0: all-or-nothing per thread
    int4 d4 = {0, 0, 0, 0};
    if (act) {
        d4 = *reinterpret_cast<const int4*>(dst + e4);
        atomicAdd(&h[d4.x >> SHIFT], 1);
        atomicAdd(&h[d4.y >> SHIFT], 1);
        atomicAdd(&h[d4.z >> SHIFT], 1);
        atomicAdd(&h[d4.w >> SHIFT], 1);
    }
    __syncthreads();
    const int hv = (t < nb) ? h[t] : 0;
    stmp[t] = hv;
    __syncthreads();
    for (int off = 1; off < 256; off <<= 1) {
        int u = (t >= off) ? stmp[t - off] : 0;
        __syncthreads();
        stmp[t] += u;
        __syncthreads();
    }
    if (t <= nb) ex[t] = stmp[t] - ((t < nb) ? h[t] : 0);  // t==nb -> chunk total
    __syncthreads();
    if (t < nb) cur[t] = ex[t];
    if (t <= nb) gbase[(size_t)blk * (nb + 1) + t] = ex[t];  // coalesced, private
    __syncthreads();
    if (act) {
        const int4 s4 = *reinterpret_cast<const int4*>(src + e4);
        int b0 = d4.x >> SHIFT, b1 = d4.y >> SHIFT;
        int b2 = d4.z >> SHIFT, b3 = d4.w >> SHIFT;
        int p0 = atomicAdd(&cur[b0], 1);
        int p1 = atomicAdd(&cur[b1], 1);
        int p2 = atomicAdd(&cur[b2], 1);
        int p3 = atomicAdd(&cur[b3], 1);
        binned[beg + p0] = (unsigned)s4.x | ((unsigned)(d4.x & (BSZ - 1)) << 17);
        binned[beg + p1] = (unsigned)s4.y | ((unsigned)(d4.y & (BSZ - 1)) << 17);
        binned[beg + p2] = (unsigned)s4.z | ((unsigned)(d4.z & (BSZ - 1)) << 17);
        binned[beg + p3] = (unsigned)s4.w | ((unsigned)(d4.w & (BSZ - 1)) << 17);
    }
}

// ---- Phase 1.5: transpose gbase[nblk][nb+1] -> gbaseT[nb+1][nblk] so k_bfill
// reads contiguous coalesced rows instead of stride-788B columns. ----
#define TD 32
__global__ __launch_bounds__(256) void k_xpose(const int* __restrict__ gbase,
                                               int* __restrict__ gbaseT,
                                               int nblk, int nbp1) {
    __shared__ int tile[TD][TD + 1];
    const int ctiles = (nbp1 + TD - 1) / TD;
    const int bx = blockIdx.x % ctiles;     // bucket-dim tile
    const int by = blockIdx.x / ctiles;     // blk-dim tile
    const int c0 = bx * TD, r0 = by * TD;
    const int tx = threadIdx.x & 31, ty = threadIdx.x >> 5;
    for (int dy = ty; dy < TD; dy += 8) {
        int r = r0 + dy, c = c0 + tx;
        tile[dy][tx] = (r < nblk && c < nbp1) ? gbase[(size_t)r * nbp1 + c] : 0;
    }
    __syncthreads();
    for (int dy = ty; dy < TD; dy += 8) {
        int r = c0 + dy, c = r0 + tx;       // row = bucket, col = blk
        if (r < nbp1 && c < nblk)
            gbaseT[(size_t)r * nblk + c] = tile[tx][dy];
    }
}

// ---- Phase 2: one 1024-thread block per bucket. Zero-atomic gather of the
// bucket's edges into LDS (len scan -> dests -> parallel copy), then count
// per node, overflow scan, packed rowptr + dinv + dummy prefill, fixed-slot
// placement. cfix[node*32+slot] = src_byte_off (dummy for slot>=deg);
// overflow edges (deg>32) -> ovf[b*OCAP + obase ...].
// rowptr[g] = ((b*OCAP+obase)<<8) | min(deg,255). ----
__global__ __launch_bounds__(1024) void k_bfill(const unsigned* __restrict__ binned,
                                                const int* __restrict__ gbaseT,
                                                int nblk, int nb,
                                                int* __restrict__ rowptr,
                                                int* __restrict__ cfix,
                                                int* __restrict__ ovf,
                                                float* __restrict__ dinv, int n) {
    __shared__ unsigned pedges[PMAX];   // 46 KB: packed edge values
    __shared__ int segarr[2048];        // lens, then exclusive prefix (dest)
    __shared__ int stmp[1024];
    __shared__ int cnt[BSZ];
    __shared__ int obase[BSZ];
    const int b = blockIdx.x;
    const int t = threadIdx.x;
    const int* rowS = gbaseT + (size_t)b * nblk;        // s0 per blk (coalesced)
    const int* rowE = gbaseT + (size_t)(b + 1) * nblk;  // s1 per blk (coalesced)
    for (int i = t; i < BSZ; i += 1024) cnt[i] = 0;
    // load lens (strided, coalesced)
    {
        int l0 = 0, l1 = 0;
        if (t < nblk)        l0 = rowE[t] - rowS[t];
        if (t + 1024 < nblk) l1 = rowE[t + 1024] - rowS[t + 1024];
        segarr[t] = l0;
        segarr[t + 1024] = l1;
    }
    __syncthreads();
    // pairwise exclusive scan over segarr[2048]: thread t owns 2t, 2t+1
    const int a0 = segarr[2 * t];
    const int a1 = segarr[2 * t + 1];
    const int ps = a0 + a1;
    stmp[t] = ps;
    __syncthreads();
    for (int off = 1; off < 1024; off <<= 1) {
        int u = (t >= off) ? stmp[t - off] : 0;
        __syncthreads();
        stmp[t] += u;
        __syncthreads();
    }
    const int ecnt = min(stmp[1023], PMAX);   // bucket total
    const int exp2_ = stmp[t] - ps;
    segarr[2 * t] = exp2_;
    segarr[2 * t + 1] = exp2_ + a0;
    __syncthreads();
    // parallel segment copy (no atomics; dests precomputed)
    for (int blk = t; blk < nblk; blk += 1024) {
        const int s0 = rowS[blk];
        const int c = rowE[blk] - s0;
        const int pos = segarr[blk];
        const unsigned* bp = binned + (size_t)blk * BIN_CH + s0;
        for (int k = 0; k < c; ++k) {
            const int d = pos + k;
            if (d < PMAX) pedges[d] = bp[k];
        }
    }
    __syncthreads();
    // pass A: per-node counts (pure LDS)
    for (int j = t; j < ecnt; j += 1024)
        atomicAdd(&cnt[pedges[j] >> 17], 1);
    __syncthreads();
    // overflow scan (512 nodes; threads 0-255 own 2 nodes each):
    // obase[j] = exclusive prefix of max(deg-32,0) within the bucket.
    const int v0 = (t < 256) ? max(cnt[2 * t] - 32, 0) : 0;
    const int v1 = (t < 256) ? max(cnt[2 * t + 1] - 32, 0) : 0;
    const int s2 = v0 + v1;
    stmp[t] = s2;
    __syncthreads();
    for (int off = 1; off < 256; off <<= 1) {
        int u = (t >= off && t < 256) ? stmp[t - off] : 0;
        __syncthreads();
        if (t < 256) stmp[t] += u;
        __syncthreads();
    }
    if (t < 256) {
        const int ex = stmp[t] - s2;
        obase[2 * t] = ex;
        obase[2 * t + 1] = ex + v0;
    }
    __syncthreads();
    const int gb9 = b << SHIFT;
    const int dum = (int)((unsigned)n << 7);
    // rowptr + dinv
    for (int j = t; j < BSZ; j += 1024) {
        const int g = gb9 + j;
        if (g < n) {
            const int dg = cnt[j];
            rowptr[g] = (int)(((unsigned)(b * OCAP + obase[j]) << 8) |
                              (unsigned)min(dg, 255));
            dinv[g] = rsqrtf((float)dg + 1.0f);
        }
    }
    // dummy prefill for slots >= deg (bucket-private 64KB cfix region)
    for (int sx = t; sx < BSZ * 32; sx += 1024) {
        const int j = sx >> 5, slot = sx & 31;
        const int g = gb9 + j;
        if (g < n && slot >= cnt[j]) cfix[(size_t)g * 32 + slot] = dum;
    }
    __syncthreads();
    for (int i = t; i < BSZ; i += 1024) cnt[i] = 0;   // becomes cursor
    __syncthreads();
    // pass B: fixed-slot place (LDS read; cfix/ovf regions bucket-private)
    for (int j = t; j < ecnt; j += 1024) {
        const unsigned e = pedges[j];
        const int lo = (int)(e >> 17);
        const int off = atomicAdd(&cnt[lo], 1);
        const int so = (int)((e & 0x1FFFFu) << 7);   // byte offset of src row
        if (off < 32) cfix[(size_t)(gb9 + lo) * 32 + off] = so;
        else          ovf[b * OCAP + obase[lo] + off - 32] = so;
    }
}

// MFMA GEMM: C16[n,64] = fp16( (A[n,K] @ W[K,64]) * dinv[row] ).
// Block = 256 threads = 4 waves; wave w computes rows rb+w*16..+15, all 64 cols.
template <int K, bool A_FP32>
__global__ __launch_bounds__(256) void k_gemm_mfma(const void* __restrict__ Av,
                                                   const float* __restrict__ W,
                                                   const float* __restrict__ dinv,
                                                   __half* __restrict__ C, int n) {
    constexpr int KP = K + 8;  // padded LDS row stride in halves (16B aligned)
    __shared__ _Float16 Wt[64 * KP];
    const int tid = threadIdx.x;
    for (int i = tid; i < K * 64; i += 256) {
        int k = i >> 6, c = i & 63;
        Wt[c * KP + k] = (_Float16)W[i];
    }
    __syncthreads();

    const int lane = tid & 63;
    const int wv = tid >> 6;
    const int r16 = lane & 15;
    const int kq = lane >> 4;                       // 0..3
    const int rb = blockIdx.x * 64 + wv * 16;
    const int arow = min(rb + r16, n - 1);          // clamped A row for this lane

    f32x4 acc[4] = {{0.f,0.f,0.f,0.f},{0.f,0.f,0.f,0.f},
                    {0.f,0.f,0.f,0.f},{0.f,0.f,0.f,0.f}};

#pragma unroll
    for (int kk = 0; kk < K; kk += 32) {
        f16x8 a;
        if (A_FP32) {
            const float* Ap = (const float*)Av + (size_t)arow * K + kk + kq * 8;
            float4 f0 = *reinterpret_cast<const float4*>(Ap);
            float4 f1 = *reinterpret_cast<const float4*>(Ap + 4);
            a[0] = (_Float16)f0.x; a[1] = (_Float16)f0.y;
            a[2] = (_Float16)f0.z; a[3] = (_Float16)f0.w;
            a[4] = (_Float16)f1.x; a[5] = (_Float16)f1.y;
            a[6] = (_Float16)f1.z; a[7] = (_Float16)f1.w;
        } else {
            const _Float16* Ap = (const _Float16*)Av + (size_t)arow * K + kk + kq * 8;
            a = *reinterpret_cast<const f16x8*>(Ap);
        }
#pragma unroll
        for (int nt = 0; nt < 4; ++nt) {
            f16x8 b = *reinterpret_cast<const f16x8*>(&Wt[(nt * 16 + r16) * KP + kk + kq * 8]);
            acc[nt] = __builtin_amdgcn_mfma_f32_16x16x32_f16(a, b, acc[nt], 0, 0, 0);
        }
    }

#pragma unroll
    for (int r = 0; r < 4; ++r) {
        const int row = rb + kq * 4 + r;
        if (row < n) {
            const float di = dinv[row];
#pragma unroll
            for (int nt = 0; nt < 4; ++nt)
                C[((size_t)row << 6) + nt * 16 + r16] = __float2half(acc[nt][r] * di);
        }
    }
}

// Accumulate 8 fp16 (one uint4) into acc[8] via v_dot2_f32_f16: one VALU op per
// value (convert+add fused, fp32 accumulate). Masks (1,0)/(0,1) keep channels
// separate; exact 1.0-multiply => bit-identical to cvt+add.
__device__ __forceinline__ void dotu4(float acc[8], uint4 u, f16x2 pl, f16x2 ph) {
    union { uint4 u4; f16x2 h[4]; } v;
    v.u4 = u;
    acc[0] = __builtin_amdgcn_fdot2(v.h[0], pl, acc[0], false);
    acc[1] = __builtin_amdgcn_fdot2(v.h[0], ph, acc[1], false);
    acc[2] = __builtin_amdgcn_fdot2(v.h[1], pl, acc[2], false);
    acc[3] = __builtin_amdgcn_fdot2(v.h[1], ph, acc[3], false);
    acc[4] = __builtin_amdgcn_fdot2(v.h[2], pl, acc[4], false);
    acc[5] = __builtin_amdgcn_fdot2(v.h[2], ph, acc[5], false);
    acc[6] = __builtin_amdgcn_fdot2(v.h[3], pl, acc[6], false);
    acc[7] = __builtin_amdgcn_fdot2(v.h[3], ph, acc[7], false);
}

// Fold partial sums across the 8 groups: after this every lane holds the full
// sums for its channel-slice p.
__device__ __forceinline__ void fold8(float acc[8]) {
#pragma unroll
    for (int m = 8; m <= 32; m <<= 1) {
#pragma unroll
        for (int j = 0; j < 8; ++j)
            acc[j] += __shfl_xor(acc[j], m, 64);
    }
}

// Rare tail (deg > 32, wave-uniform): overflow edges 32..deg-1 live at
// ovf[obeg + edge - 32]; masked to the dummy row past deg.
__device__ __forceinline__ void tail_node(const char* __restrict__ hsb,
                                          const int* __restrict__ ovf,
                                          unsigned pk, int g, int p,
                                          unsigned dum, float acc[8],
                                          f16x2 pl, f16x2 ph) {
    const int deg = (int)(pk & 255u);
    if (deg <= 32) return;                 // wave-uniform
    const int obeg = (int)(pk >> 8);
    const int t = deg - g;                 // slot k valid iff 8*k < t
    const unsigned poff = (unsigned)(p << 4);
    const unsigned dumo = dum + poff;
    const int ns = (deg + 7) >> 3;
    for (int k = 4; k < ns; k += 4) {
        const int ik = obeg + 8 * (k - 4) + g;
        unsigned c0 = (unsigned)ovf[ik]      + poff;   // slack past end is safe
        unsigned c1 = (unsigned)ovf[ik + 8]  + poff;
        unsigned c2 = (unsigned)ovf[ik + 16] + poff;
        unsigned c3 = (unsigned)ovf[ik + 24] + poff;
        const int kb = 8 * k;
        uint4 u0 = *reinterpret_cast<const uint4*>(hsb + ((kb      < t) ? c0 : dumo));
        uint4 u1 = *reinterpret_cast<const uint4*>(hsb + ((kb + 8  < t) ? c1 : dumo));
        uint4 u2 = *reinterpret_cast<const uint4*>(hsb + ((kb + 16 < t) ? c2 : dumo));
        uint4 u3 = *reinterpret_cast<const uint4*>(hsb + ((kb + 24 < t) ? c3 : dumo));
        dotu4(acc, u0, pl, ph);
        dotu4(acc, u1, pl, ph);
        dotu4(acc, u2, pl, ph);
        dotu4(acc, u3, pl, ph);
    }
}

// 4-node pipelined gather. Wave = 8 groups x 8 lanes; each group's uint4 load
// fetches one full 128B row. cfix addresses are pure arithmetic (no rowptr
// dependency): ALL 16 cfix loads then ALL 16 gather uint4s issue back-to-back
// (32 VMEM in flight). No masking in the main path -- dummy offsets are baked
// into cfix. Tails only for deg>32 (~0.02% of nodes) via rowptr/ovf (off the
// critical path).
__device__ __forceinline__ void gather_quad(const char* __restrict__ hsb,
                                            const int* __restrict__ cfix,
                                            const int* __restrict__ ovf,
                                            int ic0, int ic1, int ic2, int ic3,
                                            unsigned pk0, unsigned pk1,
                                            unsigned pk2, unsigned pk3,
                                            int g, int p, unsigned dum,
                                            float a0[8], float a1[8],
                                            float a2[8], float a3[8]) {
    const f16x2 pl = {(_Float16)1.0f, (_Float16)0.0f};
    const f16x2 ph = {(_Float16)0.0f, (_Float16)1.0f};
    const unsigned poff = (unsigned)(p << 4);
    const int b0 = ic0 * 32 + g;
    const int b1 = ic1 * 32 + g;
    const int b2 = ic2 * 32 + g;
    const int b3 = ic3 * 32 + g;
    // --- 16 cfix loads (addresses known at wave start) ---
    unsigned oa0 = (unsigned)cfix[b0]      + poff;
    unsigned oa1 = (unsigned)cfix[b0 + 8]  + poff;
    unsigned oa2 = (unsigned)cfix[b0 + 16] + poff;
    unsigned oa3 = (unsigned)cfix[b0 + 24] + poff;
    unsigned ob0 = (unsigned)cfix[b1]      + poff;
    unsigned ob1 = (unsigned)cfix[b1 + 8]  + poff;
    unsigned ob2 = (unsigned)cfix[b1 + 16] + poff;
    unsigned ob3 = (unsigned)cfix[b1 + 24] + poff;
    unsigned oc0 = (unsigned)cfix[b2]      + poff;
    unsigned oc1 = (unsigned)cfix[b2 + 8]  + poff;
    unsigned oc2 = (unsigned)cfix[b2 + 16] + poff;
    unsigned oc3 = (unsigned)cfix[b2 + 24] + poff;
    unsigned od0 = (unsigned)cfix[b3]      + poff;
    unsigned od1 = (unsigned)cfix[b3 + 8]  + poff;
    unsigned od2 = (unsigned)cfix[b3 + 16] + poff;
    unsigned od3 = (unsigned)cfix[b3 + 24] + poff;
    // --- 16 gathers ---
    uint4 ua0 = *reinterpret_cast<const uint4*>(hsb + oa0);
    uint4 ua1 = *reinterpret_cast<const uint4*>(hsb + oa1);
    uint4 ua2 = *reinterpret_cast<const uint4*>(hsb + oa2);
    uint4 ua3 = *reinterpret_cast<const uint4*>(hsb + oa3);
    uint4 ub0 = *reinterpret_cast<const uint4*>(hsb + ob0);
    uint4 ub1 = *reinterpret_cast<const uint4*>(hsb + ob1);
    uint4 ub2 = *reinterpret_cast<const uint4*>(hsb + ob2);
    uint4 ub3 = *reinterpret_cast<const uint4*>(hsb + ob3);
    uint4 uc0 = *reinterpret_cast<const uint4*>(hsb + oc0);
    uint4 uc1 = *reinterpret_cast<const uint4*>(hsb + oc1);
    uint4 uc2 = *reinterpret_cast<const uint4*>(hsb + oc2);
    uint4 uc3 = *reinterpret_cast<const uint4*>(hsb + oc3);
    uint4 ud0 = *reinterpret_cast<const uint4*>(hsb + od0);
    uint4 ud1 = *reinterpret_cast<const uint4*>(hsb + od1);
    uint4 ud2 = *reinterpret_cast<const uint4*>(hsb + od2);
    uint4 ud3 = *reinterpret_cast<const uint4*>(hsb + od3);
    // --- consume in order; later nodes' loads still in flight ---
    dotu4(a0, ua0, pl, ph);
    dotu4(a0, ua1, pl, ph);
    dotu4(a0, ua2, pl, ph);
    dotu4(a0, ua3, pl, ph);
    dotu4(a1, ub0, pl, ph);
    dotu4(a1, ub1, pl, ph);
    dotu4(a1, ub2, pl, ph);
    dotu4(a1, ub3, pl, ph);
    dotu4(a2, uc0, pl, ph);
    dotu4(a2, uc1, pl, ph);
    dotu4(a2, uc2, pl, ph);
    dotu4(a2, uc3, pl, ph);
    dotu4(a3, ud0, pl, ph);
    dotu4(a3, ud1, pl, ph);
    dotu4(a3, ud2, pl, ph);
    dotu4(a3, ud3, pl, ph);
    // --- rare tails ---
    tail_node(hsb, ovf, pk0, g, p, dum, a0, pl, ph);
    tail_node(hsb, ovf, pk1, g, p, dum, a1, pl, ph);
    tail_node(hsb, ovf, pk2, g, p, dum, a2, pl, ph);
    tail_node(hsb, ovf, pk3, g, p, dum, a3, pl, ph);
    fold8(a0);
    fold8(a1);
    fold8(a2);
    fold8(a3);
}

// Select this lane's node accumulator (nsel in 0..3).
__device__ __forceinline__ void sel4(float a[8], int nsel, const float a0[8],
                                     const float a1[8], const float a2[8],
                                     const float a3[8]) {
#pragma unroll
    for (int j = 0; j < 8; ++j) {
        float x01 = (nsel & 1) ? a1[j] : a0[j];
        float x23 = (nsel & 1) ? a3[j] : a2[j];
        a[j] = (nsel & 2) ? x23 : x01;
    }
}

// conv1 aggregation: out16 = fp16(relu(di*(sum_e hs[src_e] + hs_i) + b)).
// 4 nodes per wave; epilogue: lane group g (g<4) finalizes node i0+g.
__global__ __launch_bounds__(256) void k_agg_relu(const __half* __restrict__ hs,
                                                  const int* __restrict__ rowptr,
                                                  const int* __restrict__ cfix,
                                                  const int* __restrict__ ovf,
                                                  const float* __restrict__ dinv,
                                                  const float* __restrict__ b,
                                                  __half* __restrict__ out, int n) {
    const int wv = threadIdx.x >> 6;
    const int i0 = blockIdx.x * 16 + wv * 4;
    const int lane = threadIdx.x & 63;
    if (i0 >= n) return;
    const int g = lane >> 3, p = lane & 7;
    const int ic0 = i0;
    const int ic1 = min(i0 + 1, n - 1);
    const int ic2 = min(i0 + 2, n - 1);
    const int ic3 = min(i0 + 3, n - 1);
    const int nsel = g & 3;
    const int it = i0 + nsel;              // unclamped, for store guard
    const int iw = min(it, n - 1);
    // hoisted loads; rowptr off the critical path (tails only)
    const unsigned pk0 = (unsigned)rowptr[ic0];
    const unsigned pk1 = (unsigned)rowptr[ic1];
    const unsigned pk2 = (unsigned)rowptr[ic2];
    const unsigned pk3 = (unsigned)rowptr[ic3];
    uint4 su = *reinterpret_cast<const uint4*>(hs + ((size_t)iw << 6) + (p << 3));
    const float di = dinv[iw];
    float a0[8] = {}, a1[8] = {}, a2[8] = {}, a3[8] = {};
    gather_quad((const char*)hs, cfix, ovf, ic0, ic1, ic2, ic3,
                pk0, pk1, pk2, pk3, g, p, (unsigned)n << 7, a0, a1, a2, a3);
    if (lane < 32 && it < n) {
        const f16x2 pl = {(_Float16)1.0f, (_Float16)0.0f};
        const f16x2 ph = {(_Float16)0.0f, (_Float16)1.0f};
        float a[8];
        sel4(a, nsel, a0, a1, a2, a3);
        dotu4(a, su, pl, ph);
        float4 b0 = *reinterpret_cast<const float4*>(b + (p << 3));
        float4 b1 = *reinterpret_cast<const float4*>(b + (p << 3) + 4);
        __half2 h0 = __halves2half2(__float2half(fmaxf(fmaf(a[0], di, b0.x), 0.f)),
                                    __float2half(fmaxf(fmaf(a[1], di, b0.y), 0.f)));
        __half2 h1 = __halves2half2(__float2half(fmaxf(fmaf(a[2], di, b0.z), 0.f)),
                                    __float2half(fmaxf(fmaf(a[3], di, b0.w), 0.f)));
        __half2 h2 = __halves2half2(__float2half(fmaxf(fmaf(a[4], di, b1.x), 0.f)),
                                    __float2half(fmaxf(fmaf(a[5], di, b1.y), 0.f)));
        __half2 h3 = __halves2half2(__float2half(fmaxf(fmaf(a[6], di, b1.z), 0.f)),
                                    __float2half(fmaxf(fmaf(a[7], di, b1.w), 0.f)));
        uint4 u;
        u.x = *reinterpret_cast<unsigned*>(&h0);
        u.y = *reinterpret_cast<unsigned*>(&h1);
        u.z = *reinterpret_cast<unsigned*>(&h2);
        u.w = *reinterpret_cast<unsigned*>(&h3);
        *reinterpret_cast<uint4*>(out + ((size_t)it << 6) + (p << 3)) = u;
    }
}

// conv2 aggregation + relu + (.@Wl + bl) head, fused. 4 nodes per wave;
// group g handles node i0+(g&3) (groups 4-7 redundant); xor-1,2,4 reduce
// stays within each 8-lane group; lane p==0 of groups 0-3 stores node i0+g.
__global__ __launch_bounds__(256) void k_agg_head(const __half* __restrict__ hs,
                                                  const int* __restrict__ rowptr,
                                                  const int* __restrict__ cfix,
                                                  const int* __restrict__ ovf,
                                                  const float* __restrict__ dinv,
                                                  const float* __restrict__ b2,
                                                  const float* __restrict__ Wl,
                                                  const float* __restrict__ bl,
                                                  float* __restrict__ out, int n) {
    const int wv = threadIdx.x >> 6;
    const int i0 = blockIdx.x * 16 + wv * 4;
    const int lane = threadIdx.x & 63;
    if (i0 >= n) return;
    const int g = lane >> 3, p = lane & 7;
    const int ic0 = i0;
    const int ic1 = min(i0 + 1, n - 1);
    const int ic2 = min(i0 + 2, n - 1);
    const int ic3 = min(i0 + 3, n - 1);
    const int nsel = g & 3;
    const int it = i0 + nsel;
    const int iw = min(it, n - 1);
    const unsigned pk0 = (unsigned)rowptr[ic0];
    const unsigned pk1 = (unsigned)rowptr[ic1];
    const unsigned pk2 = (unsigned)rowptr[ic2];
    const unsigned pk3 = (unsigned)rowptr[ic3];
    uint4 su = *reinterpret_cast<const uint4*>(hs + ((size_t)iw << 6) + (p << 3));
    const float di = dinv[iw];
    float a0[8] = {}, a1[8] = {}, a2[8] = {}, a3[8] = {};
    gather_quad((const char*)hs, cfix, ovf, ic0, ic1, ic2, ic3,
                pk0, pk1, pk2, pk3, g, p, (unsigned)n << 7, a0, a1, a2, a3);
    const f16x2 pl = {(_Float16)1.0f, (_Float16)0.0f};
    const f16x2 ph = {(_Float16)0.0f, (_Float16)1.0f};
    float a[8];
    sel4(a, nsel, a0, a1, a2, a3);
    dotu4(a, su, pl, ph);
    float4 b0 = *reinterpret_cast<const float4*>(b2 + (p << 3));
    float4 b1 = *reinterpret_cast<const float4*>(b2 + (p << 3) + 4);
    float4 w0 = *reinterpret_cast<const float4*>(Wl + (p << 3));
    float4 w1 = *reinterpret_cast<const float4*>(Wl + (p << 3) + 4);
    float v = fmaxf(fmaf(a[0], di, b0.x), 0.f) * w0.x
            + fmaxf(fmaf(a[1], di, b0.y), 0.f) * w0.y
            + fmaxf(fmaf(a[2], di, b0.z), 0.f) * w0.z
            + fmaxf(fmaf(a[3], di, b0.w), 0.f) * w0.w
            + fmaxf(fmaf(a[4], di, b1.x), 0.f) * w1.x
            + fmaxf(fmaf(a[5], di, b1.y), 0.f) * w1.y
            + fmaxf(fmaf(a[6], di, b1.z), 0.f) * w1.z
            + fmaxf(fmaf(a[7], di, b1.w), 0.f) * w1.w;
    v += __shfl_xor(v, 1, 64);
    v += __shfl_xor(v, 2, 64);
    v += __shfl_xor(v, 4, 64);
    if (p == 0 && g < 4 && it < n) out[it] = v + bl[0];
}

extern "C" void kernel_launch(void* const* d_in, const int* in_sizes, int n_in,
                              void* d_out, int out_size, void* d_ws, size_t ws_size,
                              hipStream_t stream) {
    const float* x  = (const float*)d_in[0];
    const int*   ei = (const int*)d_in[1];
    const float* W1 = (const float*)d_in[2];
    const float* b1 = (const float*)d_in[3];
    const float* W2 = (const float*)d_in[4];
    const float* b2 = (const float*)d_in[5];
    const float* Wl = (const float*)d_in[6];
    const float* bl = (const float*)d_in[7];
    float* out = (float*)d_out;

    const int n = in_sizes[0] / 128;   // 100000
    const int E = in_sizes[1] / 2;     // 1600000
    const int* src = ei;
    const int* dst = ei + E;
    const int nb = (n + BSZ - 1) >> SHIFT;          // 196 buckets
    const int nblk = (E + BIN_CH - 1) / BIN_CH;     // 1563 k_bin blocks

    char* ws = (char*)d_ws;
    size_t o = 0;
    auto alloc = [&](size_t bytes) {
        void* p = ws + o;
        o = (o + bytes + 255) & ~(size_t)255;
        return p;
    };
    float* dinv    = (float*)alloc((size_t)n * 4);
    int*   rowptr  = (int*)  alloc((size_t)(n + 1) * 4);
    int*   cfix    = (int*)  alloc((size_t)n * 32 * 4);          // fixed 32-slot colidx
    int*   ovf     = (int*)  alloc(((size_t)nb * OCAP + 64) * 4);// deg>32 overflow
    int*   gbase   = (int*)  alloc((size_t)nblk * (nb + 1) * 4); // per-block bucket offsets
    int*   gbaseT  = (int*)  alloc((size_t)(nb + 1) * nblk * 4); // transposed
    __half* hs     = (__half*)alloc((size_t)(n + 1) * 64 * 2);   // +1 zeroed dummy row
    __half* bufA   = (__half*)alloc((size_t)n * 64 * 2);         // fp16 relu output
    unsigned* binned = (unsigned*)alloc(((size_t)nblk * BIN_CH) * 4);  // block-major

    // ---- CSR build (block-private counting sort; line-private stores only)
    k_bin<<<nblk, 256, 0, stream>>>(src, dst, binned, gbase, hs, n, nb, E);
    const int ctiles = (nb + 1 + TD - 1) / TD;
    const int rtiles = (nblk + TD - 1) / TD;
    k_xpose<<<ctiles * rtiles, 256, 0, stream>>>(gbase, gbaseT, nblk, nb + 1);
    k_bfill<<<nb, 1024, 0, stream>>>(binned, gbaseT, nblk, nb, rowptr, cfix,
                                     ovf, dinv, n);

    // ---- conv1 ----
    k_gemm_mfma<128, true><<<(n + 63) / 64, 256, 0, stream>>>(x, W1, dinv, hs, n);
    k_agg_relu<<<(n + 15) / 16, 256, 0, stream>>>(hs, rowptr, cfix, ovf, dinv,
                                                  b1, bufA, n);

    // ---- conv2 + head ----
    k_gemm_mfma<64, false><<<(n + 63) / 64, 256, 0, stream>>>(bufA, W2, dinv, hs, n);
    k_agg_head<<<(n + 15) / 16, 256, 0, stream>>>(hs, rowptr, cfix, ovf, dinv,
                                                  b2, Wl, bl, out, n);
}

// Round 13
// 132.862 us; speedup vs baseline: 1.1134x; 1.0221x over previous
//
#include <hip/hip_runtime.h>
#include <hip/hip_fp16.h>

// GCNRegressor: x[n,128] --GCNConv(W1)--> relu --GCNConv(W2)--> relu --@Wl+bl--> out[n]
// n=100000, E=1600000, IN=128, HID=64.
// R1-R10: CSR+gather, counting sort, fp16 features, MFMA GEMMs: 2913 -> 171 us.
// R11: 8-rows-per-VMEM gather (wave = 8 groups x 8 lanes, uint4/lane): 41.8us agg.
// R12/R13: LESSON: agg is LATENCY-bound; no branches between issue & consume.
// R14: 2 nodes/wave pipelined (16 VMEM in flight): 162 -> 148.7.
// R15/R16/R17: CSR-build experiments. RULE: every 64B line of a store stream
//      must be filled by ONE block (write amp kills otherwise).
// R18/R19: block-major binned + values-to-LDS + transposed gbase.
// R20: zero-atomic scans + 1024-thr k_bfill: 133.2. BEST.
// R21: 4-node agg (32 VMEM): neutral. R22: list indirection: 147.9 regression.
// R23: fixed-slot cfix + 4-node: 135.8 neutral. BRACKET CLOSED: the agg is
//      pinned ~34us by random-gather concurrency (86MB 8-XCD-replicated
//      refetch of hs at ~2.1TB/s effective), not by chain depth, issue rate,
//      or slot waste. R24: revert to R20 exactly -- empirical floor.

#define SHIFT 9
#define BSZ   (1 << SHIFT)     // 512 nodes per bucket
#define NBMAX 256              // >= nb = 196
#define BIN_CH 1024            // edges per k_bin block (private region)
#define PMAX  11776            // bucket edge capacity (mean 8163, +40 sigma)

using f16x8 = __attribute__((ext_vector_type(8))) _Float16;
using f16x2 = __attribute__((ext_vector_type(2))) _Float16;
using f32x4 = __attribute__((ext_vector_type(4))) float;

// ---- Phase 1: per-block counting sort into private binned region ----
// binned[blk*BIN_CH + ex[bucket] ...] sorted by bucket; gbase[blk*(nb+1)+i] =
// exclusive prefix of this block's bucket counts (row i=nb = chunk total).
// pack: src(17b) | local_node(9b)<<17. Block 0 also zeroes the dummy hs row.
__global__ __launch_bounds__(256) void k_bin(const int* __restrict__ src,
                                             const int* __restrict__ dst,
                                             unsigned* __restrict__ binned,
                                             int* __restrict__ gbase,
                                             __half* __restrict__ hs,
                                             int n, int nb, int E) {
    if (blockIdx.x == 0 && threadIdx.x < 8) {
        uint4 z = {0u, 0u, 0u, 0u};
        reinterpret_cast<uint4*>(hs + ((size_t)n << 6))[threadIdx.x] = z;
    }
    __shared__ int h[NBMAX];
    __shared__ int ex[NBMAX + 1];
    __shared__ int cur[NBMAX];
    __shared__ int stmp[256];
    const int t = threadIdx.x;
    const int blk = blockIdx.x;
    const int beg = blk * BIN_CH;
    for (int i = t; i < NBMAX; i += 256) h[i] = 0;
    __syncthreads();
    const int e4 = beg + t * 4;
    const bool act = e4 < E;               // E % 4 == 0: all-or-nothing per thread
    int4 d4 = {0, 0, 0, 0};
    if (act) {
        d4 = *reinterpret_cast<const int4*>(dst + e4);
        atomicAdd(&h[d4.x >> SHIFT], 1);
        atomicAdd(&h[d4.y >> SHIFT], 1);
        atomicAdd(&h[d4.z >> SHIFT], 1);
        atomicAdd(&h[d4.w >> SHIFT], 1);
    }
    __syncthreads();
    const int hv = (t < nb) ? h[t] : 0;
    stmp[t] = hv;
    __syncthreads();
    for (int off = 1; off < 256; off <<= 1) {
        int u = (t >= off) ? stmp[t - off] : 0;
        __syncthreads();
        stmp[t] += u;
        __syncthreads();
    }
    if (t <= nb) ex[t] = stmp[t] - ((t < nb) ? h[t] : 0);  // t==nb -> chunk total
    __syncthreads();
    if (t < nb) cur[t] = ex[t];
    if (t <= nb) gbase[(size_t)blk * (nb + 1) + t] = ex[t];  // coalesced, private
    __syncthreads();
    if (act) {
        const int4 s4 = *reinterpret_cast<const int4*>(src + e4);
        int b0 = d4.x >> SHIFT, b1 = d4.y >> SHIFT;
        int b2 = d4.z >> SHIFT, b3 = d4.w >> SHIFT;
        int p0 = atomicAdd(&cur[b0], 1);
        int p1 = atomicAdd(&cur[b1], 1);
        int p2 = atomicAdd(&cur[b2], 1);
        int p3 = atomicAdd(&cur[b3], 1);
        binned[beg + p0] = (unsigned)s4.x | ((unsigned)(d4.x & (BSZ - 1)) << 17);
        binned[beg + p1] = (unsigned)s4.y | ((unsigned)(d4.y & (BSZ - 1)) << 17);
        binned[beg + p2] = (unsigned)s4.z | ((unsigned)(d4.z & (BSZ - 1)) << 17);
        binned[beg + p3] = (unsigned)s4.w | ((unsigned)(d4.w & (BSZ - 1)) << 17);
    }
}

// ---- Phase 1.5: transpose gbase[nblk][nb+1] -> gbaseT[nb+1][nblk] so k_bfill
// reads contiguous coalesced rows instead of stride-788B columns. ----
#define TD 32
__global__ __launch_bounds__(256) void k_xpose(const int* __restrict__ gbase,
                                               int* __restrict__ gbaseT,
                                               int nblk, int nbp1) {
    __shared__ int tile[TD][TD + 1];
    const int ctiles = (nbp1 + TD - 1) / TD;
    const int bx = blockIdx.x % ctiles;     // bucket-dim tile
    const int by = blockIdx.x / ctiles;     // blk-dim tile
    const int c0 = bx * TD, r0 = by * TD;
    const int tx = threadIdx.x & 31, ty = threadIdx.x >> 5;
    for (int dy = ty; dy < TD; dy += 8) {
        int r = r0 + dy, c = c0 + tx;
        tile[dy][tx] = (r < nblk && c < nbp1) ? gbase[(size_t)r * nbp1 + c] : 0;
    }
    __syncthreads();
    for (int dy = ty; dy < TD; dy += 8) {
        int r = c0 + dy, c = r0 + tx;       // row = bucket, col = blk
        if (r < nbp1 && c < nblk)
            gbaseT[(size_t)r * nblk + c] = tile[tx][dy];
    }
}

// ---- Phase 2: one 1024-thread block per bucket. Zero-atomic build:
// (1) coalesced len load + ebeg reduction, (2) pairwise Hillis-Steele scan
// over 2048-padded lens -> per-segment LDS dest, (3) parallel segment copy
// into pedges, (4) count/scan/place from LDS. ----
// rowptr[g] = (edge_base << 8) | min(deg,255) ; colidx entry = src_byte_off.
__global__ __launch_bounds__(1024) void k_bfill(const unsigned* __restrict__ binned,
                                                const int* __restrict__ gbaseT,
                                                int nblk, int nb,
                                                int* __restrict__ rowptr,
                                                int* __restrict__ colidx,
                                                float* __restrict__ dinv, int n) {
    __shared__ unsigned pedges[PMAX];   // 46 KB: packed edge values
    __shared__ int segarr[2048];        // lens, then exclusive prefix (dest)
    __shared__ int stmp[1024];
    __shared__ int cnt[BSZ];
    __shared__ int nbase[BSZ];
    const int b = blockIdx.x;
    const int t = threadIdx.x;
    const int* rowS = gbaseT + (size_t)b * nblk;        // s0 per blk (coalesced)
    const int* rowE = gbaseT + (size_t)(b + 1) * nblk;  // s1 per blk (coalesced)
    for (int i = t; i < BSZ; i += 1024) cnt[i] = 0;
    // load lens (strided, coalesced) + ebeg partial
    int eb = 0;
    {
        int l0 = 0, l1 = 0;
        if (t < nblk)        { int s0 = rowS[t];        l0 = rowE[t] - s0;        eb += s0; }
        if (t + 1024 < nblk) { int s0 = rowS[t + 1024]; l1 = rowE[t + 1024] - s0; eb += s0; }
        segarr[t] = l0;
        segarr[t + 1024] = l1;
    }
    // ebeg reduction
    stmp[t] = eb;
    __syncthreads();
    for (int off = 512; off; off >>= 1) {
        if (t < off) stmp[t] += stmp[t + off];
        __syncthreads();
    }
    const int ebeg = stmp[0];
    __syncthreads();
    // pairwise exclusive scan over segarr[2048]: thread t owns 2t, 2t+1
    const int a0 = segarr[2 * t];
    const int a1 = segarr[2 * t + 1];
    const int ps = a0 + a1;
    stmp[t] = ps;
    __syncthreads();
    for (int off = 1; off < 1024; off <<= 1) {
        int u = (t >= off) ? stmp[t - off] : 0;
        __syncthreads();
        stmp[t] += u;
        __syncthreads();
    }
    const int ecnt = min(stmp[1023], PMAX);   // bucket total
    const int exp2_ = stmp[t] - ps;
    segarr[2 * t] = exp2_;
    segarr[2 * t + 1] = exp2_ + a0;
    __syncthreads();
    // parallel segment copy (no atomics; dests precomputed)
    for (int blk = t; blk < nblk; blk += 1024) {
        const int s0 = rowS[blk];
        const int c = rowE[blk] - s0;
        const int pos = segarr[blk];
        const unsigned* bp = binned + (size_t)blk * BIN_CH + s0;
        for (int k = 0; k < c; ++k) {
            const int d = pos + k;
            if (d < PMAX) pedges[d] = bp[k];
        }
    }
    __syncthreads();
    // pass A: per-node counts (pure LDS)
    for (int j = t; j < ecnt; j += 1024)
        atomicAdd(&cnt[pedges[j] >> 17], 1);
    __syncthreads();
    // node scan (512 nodes; threads 0-255 own 2 nodes each)
    const int c0 = (t < 256) ? cnt[2 * t] : 0;
    const int c1 = (t < 256) ? cnt[2 * t + 1] : 0;
    const int s2 = c0 + c1;
    stmp[t] = s2;
    __syncthreads();
    for (int off = 1; off < 256; off <<= 1) {
        int u = (t >= off && t < 256) ? stmp[t - off] : 0;
        __syncthreads();
        if (t < 256) stmp[t] += u;
        __syncthreads();
    }
    if (t < 256) {
        const int ex = stmp[t] - s2;
        nbase[2 * t] = ex;
        nbase[2 * t + 1] = ex + c0;
    }
    __syncthreads();
    const int gb9 = b << SHIFT;
    for (int j = t; j < BSZ; j += 1024) {
        const int g = gb9 + j;
        if (g < n) {
            rowptr[g] = (int)(((unsigned)(ebeg + nbase[j]) << 8) |
                              (unsigned)min(cnt[j], 255));
            dinv[g] = rsqrtf((float)cnt[j] + 1.0f);
        }
        cnt[j] = nbase[j];   // becomes local cursor
    }
    __syncthreads();
    // pass B: place (LDS read; colidx region is bucket-private)
    for (int j = t; j < ecnt; j += 1024) {
        const unsigned e = pedges[j];
        const int lo = (int)(e >> 17);
        const int off = atomicAdd(&cnt[lo], 1);
        colidx[ebeg + off] = (int)((e & 0x1FFFFu) << 7);  // byte offset of src row
    }
}

// MFMA GEMM: C16[n,64] = fp16( (A[n,K] @ W[K,64]) * dinv[row] ).
// Block = 256 threads = 4 waves; wave w computes rows rb+w*16..+15, all 64 cols.
template <int K, bool A_FP32>
__global__ __launch_bounds__(256) void k_gemm_mfma(const void* __restrict__ Av,
                                                   const float* __restrict__ W,
                                                   const float* __restrict__ dinv,
                                                   __half* __restrict__ C, int n) {
    constexpr int KP = K + 8;  // padded LDS row stride in halves (16B aligned)
    __shared__ _Float16 Wt[64 * KP];
    const int tid = threadIdx.x;
    for (int i = tid; i < K * 64; i += 256) {
        int k = i >> 6, c = i & 63;
        Wt[c * KP + k] = (_Float16)W[i];
    }
    __syncthreads();

    const int lane = tid & 63;
    const int wv = tid >> 6;
    const int r16 = lane & 15;
    const int kq = lane >> 4;                       // 0..3
    const int rb = blockIdx.x * 64 + wv * 16;
    const int arow = min(rb + r16, n - 1);          // clamped A row for this lane

    f32x4 acc[4] = {{0.f,0.f,0.f,0.f},{0.f,0.f,0.f,0.f},
                    {0.f,0.f,0.f,0.f},{0.f,0.f,0.f,0.f}};

#pragma unroll
    for (int kk = 0; kk < K; kk += 32) {
        f16x8 a;
        if (A_FP32) {
            const float* Ap = (const float*)Av + (size_t)arow * K + kk + kq * 8;
            float4 f0 = *reinterpret_cast<const float4*>(Ap);
            float4 f1 = *reinterpret_cast<const float4*>(Ap + 4);
            a[0] = (_Float16)f0.x; a[1] = (_Float16)f0.y;
            a[2] = (_Float16)f0.z; a[3] = (_Float16)f0.w;
            a[4] = (_Float16)f1.x; a[5] = (_Float16)f1.y;
            a[6] = (_Float16)f1.z; a[7] = (_Float16)f1.w;
        } else {
            const _Float16* Ap = (const _Float16*)Av + (size_t)arow * K + kk + kq * 8;
            a = *reinterpret_cast<const f16x8*>(Ap);
        }
#pragma unroll
        for (int nt = 0; nt < 4; ++nt) {
            f16x8 b = *reinterpret_cast<const f16x8*>(&Wt[(nt * 16 + r16) * KP + kk + kq * 8]);
            acc[nt] = __builtin_amdgcn_mfma_f32_16x16x32_f16(a, b, acc[nt], 0, 0, 0);
        }
    }

#pragma unroll
    for (int r = 0; r < 4; ++r) {
        const int row = rb + kq * 4 + r;
        if (row < n) {
            const float di = dinv[row];
#pragma unroll
            for (int nt = 0; nt < 4; ++nt)
                C[((size_t)row << 6) + nt * 16 + r16] = __float2half(acc[nt][r] * di);
        }
    }
}

// Accumulate 8 fp16 (one uint4) into acc[8] via v_dot2_f32_f16: one VALU op per
// value (convert+add fused, fp32 accumulate). Masks (1,0)/(0,1) keep channels
// separate; exact 1.0-multiply => bit-identical to cvt+add.
__device__ __forceinline__ void dotu4(float acc[8], uint4 u, f16x2 pl, f16x2 ph) {
    union { uint4 u4; f16x2 h[4]; } v;
    v.u4 = u;
    acc[0] = __builtin_amdgcn_fdot2(v.h[0], pl, acc[0], false);
    acc[1] = __builtin_amdgcn_fdot2(v.h[0], ph, acc[1], false);
    acc[2] = __builtin_amdgcn_fdot2(v.h[1], pl, acc[2], false);
    acc[3] = __builtin_amdgcn_fdot2(v.h[1], ph, acc[3], false);
    acc[4] = __builtin_amdgcn_fdot2(v.h[2], pl, acc[4], false);
    acc[5] = __builtin_amdgcn_fdot2(v.h[2], ph, acc[5], false);
    acc[6] = __builtin_amdgcn_fdot2(v.h[3], pl, acc[6], false);
    acc[7] = __builtin_amdgcn_fdot2(v.h[3], ph, acc[7], false);
}

// Fold partial sums across the 8 groups: after this every lane holds the full
// sums for its channel-slice p.
__device__ __forceinline__ void fold8(float acc[8]) {
#pragma unroll
    for (int m = 8; m <= 32; m <<= 1) {
#pragma unroll
        for (int j = 0; j < 8; ++j)
            acc[j] += __shfl_xor(acc[j], m, 64);
    }
}

// 2-node pipelined gather (R14, unchanged). Wave = 8 groups x 8 lanes; each
// group's uint4 load fetches one full 128B row. ALL loads for both nodes
// issued back-to-back (8 colidx dwords, then 8 gather uint4s = 16 VMEM in
// flight); node0's dot2s overlap node1's in-flight gathers. Unconditional 4
// slots per node (deg<=32, ~all nodes; dummy-masked loads broadcast the hot
// zero row). Tail loops only for deg>32 (~1%), after the main dots.
__device__ __forceinline__ void gather_pair(const char* __restrict__ hsb,
                                            const int* __restrict__ colidx,
                                            unsigned pk0, unsigned pk1,
                                            int g, int p, unsigned dum,
                                            float acc0[8], float acc1[8]) {
    const f16x2 pl = {(_Float16)1.0f, (_Float16)0.0f};
    const f16x2 ph = {(_Float16)0.0f, (_Float16)1.0f};
    const int beg0 = (int)(pk0 >> 8), deg0 = (int)(pk0 & 255u);
    const int beg1 = (int)(pk1 >> 8), deg1 = (int)(pk1 & 255u);
    const int t0 = deg0 - g, t1 = deg1 - g;   // slot k valid iff 8*k < t
    const unsigned poff = (unsigned)(p << 4);
    const unsigned dumo = dum + poff;
    const int ia = beg0 + g;
    const int ib = beg1 + g;
    // --- issue all 8 colidx loads (slack past E is safe) ---
    unsigned a0 = (unsigned)colidx[ia]      + poff;
    unsigned a1 = (unsigned)colidx[ia + 8]  + poff;
    unsigned a2 = (unsigned)colidx[ia + 16] + poff;
    unsigned a3 = (unsigned)colidx[ia + 24] + poff;
    unsigned b0 = (unsigned)colidx[ib]      + poff;
    unsigned b1 = (unsigned)colidx[ib + 8]  + poff;
    unsigned b2 = (unsigned)colidx[ib + 16] + poff;
    unsigned b3 = (unsigned)colidx[ib + 24] + poff;
    unsigned oa0 = (0  < t0) ? a0 : dumo;
    unsigned oa1 = (8  < t0) ? a1 : dumo;
    unsigned oa2 = (16 < t0) ? a2 : dumo;
    unsigned oa3 = (24 < t0) ? a3 : dumo;
    unsigned ob0 = (0  < t1) ? b0 : dumo;
    unsigned ob1 = (8  < t1) ? b1 : dumo;
    unsigned ob2 = (16 < t1) ? b2 : dumo;
    unsigned ob3 = (24 < t1) ? b3 : dumo;
    // --- issue all 8 gathers ---
    uint4 ua0 = *reinterpret_cast<const uint4*>(hsb + oa0);
    uint4 ua1 = *reinterpret_cast<const uint4*>(hsb + oa1);
    uint4 ua2 = *reinterpret_cast<const uint4*>(hsb + oa2);
    uint4 ua3 = *reinterpret_cast<const uint4*>(hsb + oa3);
    uint4 ub0 = *reinterpret_cast<const uint4*>(hsb + ob0);
    uint4 ub1 = *reinterpret_cast<const uint4*>(hsb + ob1);
    uint4 ub2 = *reinterpret_cast<const uint4*>(hsb + ob2);
    uint4 ub3 = *reinterpret_cast<const uint4*>(hsb + ob3);
    // --- consume node0 while node1's gathers are still in flight ---
    dotu4(acc0, ua0, pl, ph);
    dotu4(acc0, ua1, pl, ph);
    dotu4(acc0, ua2, pl, ph);
    dotu4(acc0, ua3, pl, ph);
    dotu4(acc1, ub0, pl, ph);
    dotu4(acc1, ub1, pl, ph);
    dotu4(acc1, ub2, pl, ph);
    dotu4(acc1, ub3, pl, ph);
    // --- rare tails (deg > 32), wave-uniform, after the main dots ---
    const int ns0 = (deg0 + 7) >> 3;
    for (int k = 4; k < ns0; k += 4) {
        const int ik = beg0 + 8 * k + g;
        unsigned c0 = (unsigned)colidx[ik]      + poff;
        unsigned c1 = (unsigned)colidx[ik + 8]  + poff;
        unsigned c2 = (unsigned)colidx[ik + 16] + poff;
        unsigned c3 = (unsigned)colidx[ik + 24] + poff;
        const int kb = 8 * k;
        uint4 u0 = *reinterpret_cast<const uint4*>(hsb + ((kb      < t0) ? c0 : dumo));
        uint4 u1 = *reinterpret_cast<const uint4*>(hsb + ((kb + 8  < t0) ? c1 : dumo));
        uint4 u2 = *reinterpret_cast<const uint4*>(hsb + ((kb + 16 < t0) ? c2 : dumo));
        uint4 u3 = *reinterpret_cast<const uint4*>(hsb + ((kb + 24 < t0) ? c3 : dumo));
        dotu4(acc0, u0, pl, ph);
        dotu4(acc0, u1, pl, ph);
        dotu4(acc0, u2, pl, ph);
        dotu4(acc0, u3, pl, ph);
    }
    const int ns1 = (deg1 + 7) >> 3;
    for (int k = 4; k < ns1; k += 4) {
        const int ik = beg1 + 8 * k + g;
        unsigned c0 = (unsigned)colidx[ik]      + poff;
        unsigned c1 = (unsigned)colidx[ik + 8]  + poff;
        unsigned c2 = (unsigned)colidx[ik + 16] + poff;
        unsigned c3 = (unsigned)colidx[ik + 24] + poff;
        const int kb = 8 * k;
        uint4 u0 = *reinterpret_cast<const uint4*>(hsb + ((kb      < t1) ? c0 : dumo));
        uint4 u1 = *reinterpret_cast<const uint4*>(hsb + ((kb + 8  < t1) ? c1 : dumo));
        uint4 u2 = *reinterpret_cast<const uint4*>(hsb + ((kb + 16 < t1) ? c2 : dumo));
        uint4 u3 = *reinterpret_cast<const uint4*>(hsb + ((kb + 24 < t1) ? c3 : dumo));
        dotu4(acc1, u0, pl, ph);
        dotu4(acc1, u1, pl, ph);
        dotu4(acc1, u2, pl, ph);
        dotu4(acc1, u3, pl, ph);
    }
    fold8(acc0);
    fold8(acc1);
}

// conv1 aggregation: out16 = fp16(relu(di*(sum_e hs[src_e] + hs_i) + b)).
// 2 nodes per wave; epilogue once: lanes 0-7 -> node0, lanes 8-15 -> node1.
__global__ __launch_bounds__(256) void k_agg_relu(const __half* __restrict__ hs,
                                                  const int* __restrict__ rowptr,
                                                  const int* __restrict__ colidx,
                                                  const float* __restrict__ dinv,
                                                  const float* __restrict__ b,
                                                  __half* __restrict__ out, int n) {
    const int wv = threadIdx.x >> 6;
    const int i0 = blockIdx.x * 8 + wv * 2;
    const int lane = threadIdx.x & 63;
    if (i0 >= n) return;
    const int i1 = min(i0 + 1, n - 1);
    const int g = lane >> 3, p = lane & 7;
    const int iw = (lane & 8) ? i1 : i0;
    const unsigned pk0 = (unsigned)rowptr[i0];
    const unsigned pk1 = (unsigned)rowptr[i1];
    uint4 su = *reinterpret_cast<const uint4*>(hs + ((size_t)iw << 6) + (p << 3));
    const float di = dinv[iw];
    float acc0[8] = {}, acc1[8] = {};
    gather_pair((const char*)hs, colidx, pk0, pk1, g, p, (unsigned)n << 7,
                acc0, acc1);
    if (lane < 16) {
        const f16x2 pl = {(_Float16)1.0f, (_Float16)0.0f};
        const f16x2 ph = {(_Float16)0.0f, (_Float16)1.0f};
        float a[8];
#pragma unroll
        for (int j = 0; j < 8; ++j) a[j] = (lane & 8) ? acc1[j] : acc0[j];
        dotu4(a, su, pl, ph);
        float4 b0 = *reinterpret_cast<const float4*>(b + (p << 3));
        float4 b1 = *reinterpret_cast<const float4*>(b + (p << 3) + 4);
        __half2 h0 = __halves2half2(__float2half(fmaxf(fmaf(a[0], di, b0.x), 0.f)),
                                    __float2half(fmaxf(fmaf(a[1], di, b0.y), 0.f)));
        __half2 h1 = __halves2half2(__float2half(fmaxf(fmaf(a[2], di, b0.z), 0.f)),
                                    __float2half(fmaxf(fmaf(a[3], di, b0.w), 0.f)));
        __half2 h2 = __halves2half2(__float2half(fmaxf(fmaf(a[4], di, b1.x), 0.f)),
                                    __float2half(fmaxf(fmaf(a[5], di, b1.y), 0.f)));
        __half2 h3 = __halves2half2(__float2half(fmaxf(fmaf(a[6], di, b1.z), 0.f)),
                                    __float2half(fmaxf(fmaf(a[7], di, b1.w), 0.f)));
        uint4 u;
        u.x = *reinterpret_cast<unsigned*>(&h0);
        u.y = *reinterpret_cast<unsigned*>(&h1);
        u.z = *reinterpret_cast<unsigned*>(&h2);
        u.w = *reinterpret_cast<unsigned*>(&h3);
        if (iw < n && (i0 + 1 < n || !(lane & 8)))
            *reinterpret_cast<uint4*>(out + ((size_t)iw << 6) + (p << 3)) = u;
    }
}

// conv2 aggregation + relu + (.@Wl + bl) head, fused. 2 nodes per wave;
// xor-1,2,4 reduce stays within each 8-lane group -> lane0 holds v(node0),
// lane8 holds v(node1).
__global__ __launch_bounds__(256) void k_agg_head(const __half* __restrict__ hs,
                                                  const int* __restrict__ rowptr,
                                                  const int* __restrict__ colidx,
                                                  const float* __restrict__ dinv,
                                                  const float* __restrict__ b2,
                                                  const float* __restrict__ Wl,
                                                  const float* __restrict__ bl,
                                                  float* __restrict__ out, int n) {
    const int wv = threadIdx.x >> 6;
    const int i0 = blockIdx.x * 8 + wv * 2;
    const int lane = threadIdx.x & 63;
    if (i0 >= n) return;
    const int i1 = min(i0 + 1, n - 1);
    const int g = lane >> 3, p = lane & 7;
    const int iw = (lane & 8) ? i1 : i0;
    const unsigned pk0 = (unsigned)rowptr[i0];
    const unsigned pk1 = (unsigned)rowptr[i1];
    uint4 su = *reinterpret_cast<const uint4*>(hs + ((size_t)iw << 6) + (p << 3));
    const float di = dinv[iw];
    float acc0[8] = {}, acc1[8] = {};
    gather_pair((const char*)hs, colidx, pk0, pk1, g, p, (unsigned)n << 7,
                acc0, acc1);
    const f16x2 pl = {(_Float16)1.0f, (_Float16)0.0f};
    const f16x2 ph = {(_Float16)0.0f, (_Float16)1.0f};
    float a[8];
#pragma unroll
    for (int j = 0; j < 8; ++j) a[j] = (lane & 8) ? acc1[j] : acc0[j];
    dotu4(a, su, pl, ph);
    float4 b0 = *reinterpret_cast<const float4*>(b2 + (p << 3));
    float4 b1 = *reinterpret_cast<const float4*>(b2 + (p << 3) + 4);
    float4 w0 = *reinterpret_cast<const float4*>(Wl + (p << 3));
    float4 w1 = *reinterpret_cast<const float4*>(Wl + (p << 3) + 4);
    float v = fmaxf(fmaf(a[0], di, b0.x), 0.f) * w0.x
            + fmaxf(fmaf(a[1], di, b0.y), 0.f) * w0.y
            + fmaxf(fmaf(a[2], di, b0.z), 0.f) * w0.z
            + fmaxf(fmaf(a[3], di, b0.w), 0.f) * w0.w
            + fmaxf(fmaf(a[4], di, b1.x), 0.f) * w1.x
            + fmaxf(fmaf(a[5], di, b1.y), 0.f) * w1.y
            + fmaxf(fmaf(a[6], di, b1.z), 0.f) * w1.z
            + fmaxf(fmaf(a[7], di, b1.w), 0.f) * w1.w;
    v += __shfl_xor(v, 1, 64);
    v += __shfl_xor(v, 2, 64);
    v += __shfl_xor(v, 4, 64);
    if (lane == 0) out[i0] = v + bl[0];
    if (lane == 8 && i0 + 1 < n) out[i1] = v + bl[0];
}

extern "C" void kernel_launch(void* const* d_in, const int* in_sizes, int n_in,
                              void* d_out, int out_size, void* d_ws, size_t ws_size,
                              hipStream_t stream) {
    const float* x  = (const float*)d_in[0];
    const int*   ei = (const int*)d_in[1];
    const float* W1 = (const float*)d_in[2];
    const float* b1 = (const float*)d_in[3];
    const float* W2 = (const float*)d_in[4];
    const float* b2 = (const float*)d_in[5];
    const float* Wl = (const float*)d_in[6];
    const float* bl = (const float*)d_in[7];
    float* out = (float*)d_out;

    const int n = in_sizes[0] / 128;   // 100000
    const int E = in_sizes[1] / 2;     // 1600000
    const int* src = ei;
    const int* dst = ei + E;
    const int nb = (n + BSZ - 1) >> SHIFT;          // 196 buckets
    const int nblk = (E + BIN_CH - 1) / BIN_CH;     // 1563 k_bin blocks

    char* ws = (char*)d_ws;
    size_t o = 0;
    auto alloc = [&](size_t bytes) {
        void* p = ws + o;
        o = (o + bytes + 255) & ~(size_t)255;
        return p;
    };
    float* dinv    = (float*)alloc((size_t)n * 4);
    int*   rowptr  = (int*)  alloc((size_t)(n + 1) * 4);
    int*   colidx  = (int*)  alloc(((size_t)E + 64) * 4);        // +slack for unrolled reads
    int*   gbase   = (int*)  alloc((size_t)nblk * (nb + 1) * 4); // per-block bucket offsets
    int*   gbaseT  = (int*)  alloc((size_t)(nb + 1) * nblk * 4); // transposed
    __half* hs     = (__half*)alloc((size_t)(n + 1) * 64 * 2);   // +1 zeroed dummy row
    __half* bufA   = (__half*)alloc((size_t)n * 64 * 2);         // fp16 relu output
    unsigned* binned = (unsigned*)alloc(((size_t)nblk * BIN_CH) * 4);  // block-major

    // ---- CSR build (block-private counting sort; line-private stores only)
    k_bin<<<nblk, 256, 0, stream>>>(src, dst, binned, gbase, hs, n, nb, E);
    const int ctiles = (nb + 1 + TD - 1) / TD;
    const int rtiles = (nblk + TD - 1) / TD;
    k_xpose<<<ctiles * rtiles, 256, 0, stream>>>(gbase, gbaseT, nblk, nb + 1);
    k_bfill<<<nb, 1024, 0, stream>>>(binned, gbaseT, nblk, nb, rowptr, colidx,
                                     dinv, n);

    // ---- conv1 ----
    k_gemm_mfma<128, true><<<(n + 63) / 64, 256, 0, stream>>>(x, W1, dinv, hs, n);
    k_agg_relu<<<(n + 7) / 8, 256, 0, stream>>>(hs, rowptr, colidx, dinv, b1, bufA, n);

    // ---- conv2 + head ----
    k_gemm_mfma<64, false><<<(n + 63) / 64, 256, 0, stream>>>(bufA, W2, dinv, hs, n);
    k_agg_head<<<(n + 7) / 8, 256, 0, stream>>>(hs, rowptr, colidx, dinv, b2, Wl, bl,
                                                out, n);
}